// Round 6
// baseline (556.484 us; speedup 1.0000x reference)
//
#include <hip/hip_runtime.h>
#include <hip/hip_bf16.h>
#include <hip/hip_fp16.h>
#include <stdint.h>

#define N_NODES 100000
#define N_EDGES 1600000
#define ET (N_EDGES + N_NODES)   // edges + self-loops
#define HID 128
#define C2 40
#define F2 80
#define NEG 0.2f
#define BN_EPS 1e-5f
#define NBUCK 391                // ceil(100000/256) coarse buckets (256 nodes each)
#define BCAP 6144                // slots per bucket (mean 4608, sd 66 -> +23 sigma)
#define NBB 640                  // bin-pass blocks
#define EPB ((ET + NBB - 1) / NBB)
#define CH2 256                  // per-NODE LDS edge cache in k_agg2

typedef __hip_bfloat16 bf16;
typedef __attribute__((ext_vector_type(8))) short s8v;          // 8 bf16 MFMA A/B frag
typedef __attribute__((ext_vector_type(4))) float f4v;          // MFMA C/D frag
typedef __attribute__((ext_vector_type(4))) unsigned int u4v;
typedef __attribute__((ext_vector_type(2))) unsigned int u2v;

__device__ __forceinline__ float b2f(bf16 v){ return __bfloat162float(v); }
__device__ __forceinline__ float rdf(const void* p, size_t i, int isb){
    return isb ? b2f(((const bf16*)p)[i]) : ((const float*)p)[i];
}
__device__ __forceinline__ unsigned short f2bb(float v){
    bf16 h = __float2bfloat16(v);
    return *(unsigned short*)&h;
}
__device__ __forceinline__ uint32_t pack2(float a, float b){
    return (uint32_t)f2bb(a) | ((uint32_t)f2bb(b) << 16);
}
__device__ __forceinline__ uint32_t packh2(float a, float b){
    return (uint32_t)__half_as_ushort(__float2half(a))
         | ((uint32_t)__half_as_ushort(__float2half(b)) << 16);
}
__device__ __forceinline__ float lo16(uint32_t u){ return __uint_as_float(u << 16); }
__device__ __forceinline__ float hi16(uint32_t u){ return __uint_as_float(u & 0xFFFF0000u); }
__device__ __forceinline__ float hcvt(uint32_t w, int sh){
    return __half2float(__ushort_as_half((unsigned short)((w >> sh) & 0xFFFFu)));
}
// decode 15-bit (sign-stripped half) weight from a (src<<15)|w15 record
__device__ __forceinline__ float w15f(uint32_t w){
    return __half2float(__ushort_as_half((unsigned short)(w & 0x7FFFu)));
}

// ---------------- init: dtype flag + zero gcur/stats ------------------------
__global__ __launch_bounds__(256) void k_init(
    const uint32_t* __restrict__ w1bits, int* __restrict__ flag,
    int* __restrict__ gcur, float* __restrict__ stats)
{
    __shared__ int cnt;
    int t = threadIdx.x;
    if (t == 0) cnt = 0;
    __syncthreads();
    uint32_t b = w1bits[t];
    float lo = __uint_as_float((b & 0xFFFFu) << 16);
    float a = fabsf(lo);
    if (a > 1e-8f && a < 1.0f) atomicAdd(&cnt, 1);
    for (int i = t; i < NBUCK; i += 256) gcur[i] = 0;
    stats[t] = 0.f;
    __syncthreads();
    if (t == 0) *flag = (cnt >= 192) ? 1 : 0;
}

// ---------------- GEMM1 (MFMA): h1 = x @ W1, + fused att1 dots --------------
__global__ __launch_bounds__(256) void k_gemm1(
    const void* __restrict__ x, const void* __restrict__ W1,
    const void* __restrict__ attS, const void* __restrict__ attD,
    const int* __restrict__ flag, unsigned short* __restrict__ h1,
    float* __restrict__ aS, float* __restrict__ aD)
{
    __shared__ __attribute__((aligned(16))) unsigned short wT[128*132]; // 33.8 KB
    const int isb = *flag;
    const int tid = threadIdx.x;
    if (isb) {
        const unsigned short* w = (const unsigned short*)W1;
        for (int idx = tid; idx < 128*128; idx += 256){
            int k = idx >> 7, n = idx & 127;
            wT[n*132 + k] = w[idx];
        }
    } else {
        const float* w = (const float*)W1;
        for (int idx = tid; idx < 128*128; idx += 256){
            int k = idx >> 7, n = idx & 127;
            wT[n*132 + k] = f2bb(w[idx]);
        }
    }
    __syncthreads();

    const int w4 = tid >> 6, lane = tid & 63, quad = lane >> 4, l16 = lane & 15;
    const int rowbase = blockIdx.x*32 + (w4 >> 1)*16;   // 3125*32 = 100000 exact
    const int colbase = (w4 & 1)*64;
    const int head = w4 & 1;

    s8v bfr[4][4];
    float asv[4], adv[4];
    #pragma unroll
    for (int ct = 0; ct < 4; ct++){
        int n = colbase + ct*16 + l16;
        asv[ct] = rdf(attS, n, isb);
        adv[ct] = rdf(attD, n, isb);
        #pragma unroll
        for (int s = 0; s < 4; s++){
            int k0 = s*32 + quad*8;
            const unsigned short* p = &wT[n*132 + k0];
            u2v a = *(const u2v*)p, b = *(const u2v*)(p+4);
            union { u4v u; s8v s; } cv; cv.u = (u4v){a[0],a[1],b[0],b[1]};
            bfr[ct][s] = cv.s;
        }
    }

    f4v acc[4];
    #pragma unroll
    for (int ct = 0; ct < 4; ct++) acc[ct] = (f4v){0.f,0.f,0.f,0.f};

    const int m = rowbase + l16;
    #pragma unroll
    for (int s = 0; s < 4; s++){
        int k0 = s*32 + quad*8;
        s8v af;
        if (isb){
            union { u4v u; s8v s; } cv;
            cv.u = *(const u4v*)((const unsigned short*)x + (size_t)m*128 + k0);
            af = cv.s;
        } else {
            const float* xp = (const float*)x + (size_t)m*128 + k0;
            f4v f0 = *(const f4v*)xp, f1 = *(const f4v*)(xp+4);
            union { u4v u; s8v s; } cv;
            cv.u = (u4v){pack2(f0[0],f0[1]), pack2(f0[2],f0[3]),
                         pack2(f1[0],f1[1]), pack2(f1[2],f1[3])};
            af = cv.s;
        }
        #pragma unroll
        for (int ct = 0; ct < 4; ct++)
            acc[ct] = __builtin_amdgcn_mfma_f32_16x16x32_bf16(af, bfr[ct][s], acc[ct], 0,0,0);
    }

    // C/D: col = lane&15, row = quad*4 + reg
    #pragma unroll
    for (int ct = 0; ct < 4; ct++){
        int col = colbase + ct*16 + l16;
        #pragma unroll
        for (int r = 0; r < 4; r++){
            int row = rowbase + quad*4 + r;
            h1[(size_t)row*128 + col] = f2bb(acc[ct][r]);
        }
    }

    // fused att1: per row, reduce acc*att over wave's 64 cols (one head).
    #pragma unroll
    for (int r = 0; r < 4; r++){
        float vs = 0.f, vd = 0.f;
        #pragma unroll
        for (int ct = 0; ct < 4; ct++){ vs += acc[ct][r]*asv[ct]; vd += acc[ct][r]*adv[ct]; }
        #pragma unroll
        for (int o = 1; o < 16; o <<= 1){
            vs += __shfl_xor(vs, o, 64);
            vd += __shfl_xor(vd, o, 64);
        }
        if (l16 == 0){
            int row = rowbase + quad*4 + r;
            aS[row*2 + head] = vs;
            aD[row*2 + head] = vd;
        }
    }
}

// ---------------- CSR pass 1: LDS-binned coarse scatter ---------------------
__global__ __launch_bounds__(256) void k_bin(
    const int* __restrict__ esrc, const int* __restrict__ edst,
    int* __restrict__ gcur, uint32_t* __restrict__ staging)
{
    __shared__ int cnt[NBUCK];
    __shared__ int bb[NBUCK];
    const int t = threadIdx.x;
    for (int i = t; i < NBUCK; i += 256) cnt[i] = 0;
    __syncthreads();
    const int e0 = blockIdx.x * EPB;
    const int e1 = (e0 + EPB < ET) ? e0 + EPB : ET;
    for (int e = e0 + t; e < e1; e += 256){
        int d = (e < N_EDGES) ? edst[e] : e - N_EDGES;
        atomicAdd(&cnt[d >> 8], 1);
    }
    __syncthreads();
    // rotate flush order by block to avoid lockstep per-address atomic chains
    const int bofs = (int)(blockIdx.x % NBUCK);
    for (int i = t; i < NBUCK; i += 256){
        int bkt = i + bofs; if (bkt >= NBUCK) bkt -= NBUCK;
        int c = cnt[bkt];
        bb[bkt] = c ? atomicAdd(&gcur[bkt], c) : 0;
        cnt[bkt] = 0;
    }
    __syncthreads();
    for (int e = e0 + t; e < e1; e += 256){
        int d, s;
        if (e < N_EDGES){ s = esrc[e]; d = edst[e]; } else { s = d = e - N_EDGES; }
        int b = d >> 8;
        int r = atomicAdd(&cnt[b], 1);
        int p = bb[b] + r;
        if (p < BCAP) staging[(size_t)b*BCAP + p] = ((uint32_t)s << 8) | (uint32_t)(d & 255);
    }
}

// ---------------- CSR pass 2: counting sort + fused layer-1 weights ---------
// After building the per-bucket CSR in LDS, thread t (= local node t) computes
// its edges' layer-1 attention exps ONCE, writes two 4B records per slot:
//   wb0[slot] = (src<<15) | half_bits(exp_h0)   (half has no sign bit: exact)
//   wb1[slot] = (src<<15) | half_bits(exp_h1)
// and per-node float denominators den[d*2+h]. wb0 reuses the staging buffer
// (all staging reads for this bucket complete before the weight phase).
__global__ __launch_bounds__(256) void k_sort(
    const int* __restrict__ gcur, uint32_t* stg /* in: staging, out: wb0 */,
    const float* __restrict__ aS, const float* __restrict__ aD,
    int* __restrict__ deg, int* __restrict__ cur,
    uint32_t* __restrict__ wb1, float* __restrict__ den)
{
    __shared__ int h[256], sc[256], rk[256];
    __shared__ int lsrc[BCAP];
    const int b = blockIdx.x;
    const int t = threadIdx.x;
    const int base = b * BCAP;
    int cnt = gcur[b];
    if (cnt > BCAP) cnt = BCAP;
    h[t] = 0; rk[t] = 0;
    __syncthreads();
    for (int i = t; i < cnt; i += 256)
        atomicAdd(&h[stg[base + i] & 255u], 1);
    __syncthreads();
    sc[t] = h[t];
    __syncthreads();
    for (int off = 1; off < 256; off <<= 1){
        int v = (t >= off) ? sc[t - off] : 0;
        __syncthreads();
        sc[t] += v;
        __syncthreads();
    }
    int dg = b*256 + t;
    if (dg < N_NODES){
        deg[dg] = h[t];
        cur[dg] = base + sc[t];    // end pointer; start = end - deg
    }
    __syncthreads();
    for (int i = t; i < cnt; i += 256){
        uint32_t w = stg[base + i];
        int dl = w & 255u;
        int r = atomicAdd(&rk[dl], 1);
        lsrc[sc[dl] - h[dl] + r] = (int)(w >> 8);
    }
    __syncthreads();
    // ---- fused weight phase (needs gemm1's aS/aD; stream order guarantees) ----
    if (dg < N_NODES){
        int myDeg = h[t];
        int myStart = sc[t] - h[t];
        float2 adv = *(const float2*)(aD + (size_t)dg*2);
        float den0 = 0.f, den1 = 0.f;
        for (int i = 0; i < myDeg; i++){
            int s = lsrc[myStart + i];
            float2 as = *(const float2*)(aS + (size_t)s*2);
            float al0 = as.x + adv.x, al1 = as.y + adv.y;
            al0 = al0 > 0.f ? al0 : NEG*al0;
            al1 = al1 > 0.f ? al1 : NEG*al1;
            float e0 = __expf(al0), e1 = __expf(al1);
            den0 += e0; den1 += e1;
            uint32_t sb = (uint32_t)s << 15;
            uint32_t p0 = (uint32_t)__half_as_ushort(__float2half(e0)) & 0x7FFFu;
            uint32_t p1 = (uint32_t)__half_as_ushort(__float2half(e1)) & 0x7FFFu;
            stg[base + myStart + i] = sb | p0;   // wb0
            wb1[base + myStart + i] = sb | p1;
        }
        den[(size_t)dg*2]     = den0;
        den[(size_t)dg*2 + 1] = den1;
    }
}

// ---------------- layer-1 agg: 8-way XCD feature-slice split ----------------
// h1 rows (256B) are cut into 8 x 32B slices; task = (node, slice) with
// slice = blockIdx&7. Under round-robin block->XCD mapping each XCD touches
// only its 3.2 MB slice of the table -> fits the 4 MB L2 -> gathers become
// L2 hits; HBM table fetch ~= compulsory 25.6 MB. Weights/srcs come from the
// precomputed wb records (no exp/phase-1 here at all, no LDS). Per half-wave
// task: 2 lanes/edge x dwordx4, 16 edges/round, 2 rounds unrolled in flight;
// fold = 4 xor rounds; epilogue normalizes by den[d*2+h] (slice head-pure).
// Non-temporal on wb reads + out writes to keep the table hot in L2.
__global__ __launch_bounds__(256) void k_agg1(
    const int* __restrict__ cur, const int* __restrict__ deg,
    const uint32_t* __restrict__ wb0, const uint32_t* __restrict__ wb1,
    const float* __restrict__ den, const uint32_t* __restrict__ h1u,
    uint32_t* __restrict__ out1u)
{
    const int bx = blockIdx.x;
    const int k = bx & 7;                // slice class -> XCD affinity
    const int grp = bx >> 3;             // 12500 groups x 8 nodes
    const int h = k >> 2;                // head: slices 0-3 h0, 4-7 h1
    const uint32_t* __restrict__ wb = h ? wb1 : wb0;
    const int wv = threadIdx.x >> 6;
    const int l = threadIdx.x & 63;
    const int half = l >> 5, ll = l & 31;
    const int d = grp*8 + wv*2 + half;   // < 100000 exact
    const int sub = ll & 1, epair = ll >> 1;
    const uint32_t kofs = (uint32_t)(k*32 + sub*16);
    int end = cur[d];
    int dgv = deg[d];
    int start = end - dgv;
    float dh = den[(size_t)d*2 + h];
    float acc[8];
    #pragma unroll
    for (int q = 0; q < 8; q++) acc[q] = 0.f;
    int rm = (dgv + 15) >> 4;
    rm = max(rm, __shfl_xor(rm, 32, 64));   // uniform trip count per wave
    const char* hb = (const char*)h1u;

#define GF(G, W) { float Wf = (W); \
    acc[0] += Wf*lo16((G)[0]); acc[1] += Wf*hi16((G)[0]); \
    acc[2] += Wf*lo16((G)[1]); acc[3] += Wf*hi16((G)[1]); \
    acc[4] += Wf*lo16((G)[2]); acc[5] += Wf*hi16((G)[2]); \
    acc[6] += Wf*lo16((G)[3]); acc[7] += Wf*hi16((G)[3]); }

    int t = 0;
    for (; t + 2 <= rm; t += 2){         // 32 edges, 2 gathers/lane in flight
        int j0 = start + (t << 4) + epair;
        int j1 = j0 + 16;
        bool v0 = j0 < end, v1 = j1 < end;
        uint32_t w0 = __builtin_nontemporal_load(wb + (v0 ? j0 : start));
        uint32_t w1 = __builtin_nontemporal_load(wb + (v1 ? j1 : start));
        u4v G0 = *(const u4v*)(hb + (((w0 >> 15) << 8) + kofs));
        u4v G1 = *(const u4v*)(hb + (((w1 >> 15) << 8) + kofs));
        float f0 = v0 ? w15f(w0) : 0.f;
        float f1 = v1 ? w15f(w1) : 0.f;
        GF(G0, f0);
        GF(G1, f1);
    }
    if (t < rm){
        int j0 = start + (t << 4) + epair;
        bool v0 = j0 < end;
        uint32_t w0 = __builtin_nontemporal_load(wb + (v0 ? j0 : start));
        u4v G0 = *(const u4v*)(hb + (((w0 >> 15) << 8) + kofs));
        float f0 = v0 ? w15f(w0) : 0.f;
        GF(G0, f0);
    }
#undef GF
    // fold 16 edge-pairs onto the 2 sub-lanes of each half
    #pragma unroll
    for (int q = 0; q < 8; q++){
        acc[q] += __shfl_xor(acc[q], 2, 64);
        acc[q] += __shfl_xor(acc[q], 4, 64);
        acc[q] += __shfl_xor(acc[q], 8, 64);
        acc[q] += __shfl_xor(acc[q], 16, 64);
    }
    if (ll < 2){
        float rr = 1.f / fmaxf(dh, 1e-20f);
        u4v o;
        #pragma unroll
        for (int q = 0; q < 4; q++) o[q] = pack2(acc[2*q]*rr, acc[2*q+1]*rr);
        __builtin_nontemporal_store(o,
            (u4v*)(out1u + (size_t)d*64 + 8*k + 4*ll));
    }
}

// ---------------- BatchNorm stats: per-block LDS reduce, then 1 atomic ------
__global__ __launch_bounds__(256) void k_bnstats(
    const uint32_t* __restrict__ out1u, float* __restrict__ stats)
{
    __shared__ float red[4][64][4];      // wave x feat-pair x {s0,s1,q0,q1} = 4 KB
    int fp = threadIdx.x & 63;
    int wv = threadIdx.x >> 6;
    float s0 = 0.f, q0 = 0.f, s1 = 0.f, q1 = 0.f;
    for (int r = blockIdx.x*4 + wv; r < N_NODES; r += 512){
        uint32_t u = out1u[(size_t)r*64 + fp];
        float f0 = lo16(u), f1 = hi16(u);
        s0 += f0; q0 += f0*f0; s1 += f1; q1 += f1*f1;
    }
    red[wv][fp][0] = s0; red[wv][fp][1] = s1;
    red[wv][fp][2] = q0; red[wv][fp][3] = q1;
    __syncthreads();
    if (threadIdx.x < 64){
        int l = threadIdx.x;
        float a0=0.f, a1=0.f, b0=0.f, b1=0.f;
        #pragma unroll
        for (int w = 0; w < 4; w++){
            a0 += red[w][l][0]; a1 += red[w][l][1];
            b0 += red[w][l][2]; b1 += red[w][l][3];
        }
        unsafeAtomicAdd(&stats[2*l],       a0);
        unsafeAtomicAdd(&stats[2*l+1],     a1);
        unsafeAtomicAdd(&stats[128+2*l],   b0);
        unsafeAtomicAdd(&stats[128+2*l+1], b1);
    }
}

// ---------------- GEMM2 (MFMA): h2 = BN(out1) @ W2, + fused att2, BN-fin ----
__global__ __launch_bounds__(256) void k_gemm2(
    const unsigned short* __restrict__ out1b, const float* __restrict__ stats,
    const void* __restrict__ gamma, const void* __restrict__ beta,
    const void* __restrict__ W2, const void* __restrict__ attS,
    const void* __restrict__ attD, const int* __restrict__ flag,
    unsigned short* __restrict__ h2, float* __restrict__ aS, float* __restrict__ aD)
{
    __shared__ __attribute__((aligned(16))) unsigned short wT[80*132]; // 21.1 KB
    __shared__ float scl[128], shl[128];
    const int isb = *flag;
    const int tid = threadIdx.x;
    for (int idx = tid; idx < 128*80; idx += 256){
        int k = idx / 80, n = idx - k*80;
        wT[n*132 + k] = isb ? ((const unsigned short*)W2)[idx]
                            : f2bb(((const float*)W2)[idx]);
    }
    if (tid < 128){   // inline BN finalize
        float mean = stats[tid] * (1.f / N_NODES);
        float var = fmaxf(stats[128+tid] * (1.f / N_NODES) - mean*mean, 0.f);
        float rs = rsqrtf(var + BN_EPS);
        float sc = rdf(gamma, tid, isb) * rs;
        scl[tid] = sc;
        shl[tid] = rdf(beta, tid, isb) - mean*sc;
    }
    __syncthreads();

    const int w4 = tid >> 6, lane = tid & 63, quad = lane >> 4, l16 = lane & 15;
    const int rowbase = blockIdx.x*64 + w4*16;

    s8v bfr[5][4];
    float asv[5], adv[5];
    #pragma unroll
    for (int ct = 0; ct < 5; ct++){
        int n = ct*16 + l16;
        asv[ct] = rdf(attS, n, isb);
        adv[ct] = rdf(attD, n, isb);
        #pragma unroll
        for (int s = 0; s < 4; s++){
            int k0 = s*32 + quad*8;
            const unsigned short* p = &wT[n*132 + k0];
            u2v a = *(const u2v*)p, b = *(const u2v*)(p+4);
            union { u4v u; s8v s; } cv; cv.u = (u4v){a[0],a[1],b[0],b[1]};
            bfr[ct][s] = cv.s;
        }
    }

    f4v acc[5];
    #pragma unroll
    for (int ct = 0; ct < 5; ct++) acc[ct] = (f4v){0.f,0.f,0.f,0.f};

    int m = rowbase + l16;
    int mc = m < N_NODES ? m : N_NODES - 1;
    #pragma unroll
    for (int s = 0; s < 4; s++){
        int k0 = s*32 + quad*8;
        union { u4v u; s8v s8; } cin;
        cin.u = *(const u4v*)(out1b + (size_t)mc*128 + k0);
        u4v up;
        #pragma unroll
        for (int i = 0; i < 4; i++){
            float f0 = lo16(cin.u[i]), f1 = hi16(cin.u[i]);
            int k = k0 + 2*i;
            up[i] = pack2(f0*scl[k] + shl[k], f1*scl[k+1] + shl[k+1]);
        }
        union { u4v u; s8v s8; } cv; cv.u = up;
        #pragma unroll
        for (int ct = 0; ct < 5; ct++)
            acc[ct] = __builtin_amdgcn_mfma_f32_16x16x32_bf16(cv.s8, bfr[ct][s], acc[ct], 0,0,0);
    }

    #pragma unroll
    for (int ct = 0; ct < 5; ct++){
        int col = ct*16 + l16;
        #pragma unroll
        for (int r = 0; r < 4; r++){
            int row = rowbase + quad*4 + r;
            if (row < N_NODES) h2[(size_t)row*80 + col] = f2bb(acc[ct][r]);
        }
    }

    // fused att2: head0 = cols 0..39, head1 = cols 40..79.
    #pragma unroll
    for (int r = 0; r < 4; r++){
        float vs0 = 0.f, vs1 = 0.f, vd0 = 0.f, vd1 = 0.f;
        #pragma unroll
        for (int ct = 0; ct < 5; ct++){
            int col = ct*16 + l16;
            float ps = acc[ct][r]*asv[ct], pd = acc[ct][r]*adv[ct];
            if (col < 40){ vs0 += ps; vd0 += pd; } else { vs1 += ps; vd1 += pd; }
        }
        #pragma unroll
        for (int o = 1; o < 16; o <<= 1){
            vs0 += __shfl_xor(vs0, o, 64); vs1 += __shfl_xor(vs1, o, 64);
            vd0 += __shfl_xor(vd0, o, 64); vd1 += __shfl_xor(vd1, o, 64);
        }
        if (l16 == 0){
            int row = rowbase + quad*4 + r;
            if (row < N_NODES){
                aS[row*2 + 0] = vs0; aS[row*2 + 1] = vs1;
                aD[row*2 + 0] = vd0; aD[row*2 + 1] = vd1;
            }
        }
    }
}

// ---------------- layer-2 agg: 2 nodes/wave, 10 lanes/edge x dwordx4 --------
// (R3 form — best measured.) src now decoded from wb0 records (w >> 15).
__global__ __launch_bounds__(256) void k_agg2(
    const int* __restrict__ cur, const int* __restrict__ deg,
    const uint32_t* __restrict__ wb0, const float* __restrict__ aS,
    const float* __restrict__ aD, const uint32_t* __restrict__ h2u,
    const void* __restrict__ b2v, const int* __restrict__ flag,
    void* __restrict__ out)
{
    __shared__ uint2 lse[4][2][CH2 + 4];   // 16.6 KB
    const int wv = threadIdx.x >> 6;
    const int l = threadIdx.x & 63;
    const int half = l >> 5, ll = l & 31;
    const int d = blockIdx.x*8 + wv*2 + half;   // 12500*8 = 100000 exact
    const int isb = *flag;
    const int c = ll % 10;               // feature slot within edge
    const int g = ll / 10;               // edge group 0..2 (3 = idle lanes)
    const bool act = ll < 30;
    const int gq = act ? g : 0;          // safe lse index for idle lanes
    const uint32_t c16 = (uint32_t)(c*16);
    int end   = cur[d];
    int start = end - deg[d];
    float2 ad = *(const float2*)(aD + d*2);
    const int sh = (c >= 5) ? 16 : 0;    // cols 8c..8c+7: head1 iff 8c >= 40
    float den0 = 0.f, den1 = 0.f;
    float acc[8];
    #pragma unroll
    for (int k = 0; k < 8; k++) acc[k] = 0.f;
    const char* hb = (const char*)h2u;

#define G2(P, W) { u4v Gx = *(const u4v*)(hb + ((P).x + c16)); \
    float Wf = (W); \
    acc[0] += Wf*lo16(Gx[0]); acc[1] += Wf*hi16(Gx[0]); \
    acc[2] += Wf*lo16(Gx[1]); acc[3] += Wf*hi16(Gx[1]); \
    acc[4] += Wf*lo16(Gx[2]); acc[5] += Wf*hi16(Gx[2]); \
    acc[6] += Wf*lo16(Gx[3]); acc[7] += Wf*hi16(Gx[3]); }

    for (int c0 = start; c0 < end; c0 += CH2){
        int c1 = (c0 + CH2 < end) ? c0 + CH2 : end;
        int n = c1 - c0;
        // phase 1: half's 32 lanes parallel over this node's edges
        for (int j = c0 + ll; j < c1; j += 32){
            uint32_t s = __builtin_nontemporal_load(wb0 + j) >> 15;
            float2 as = *(const float2*)((const char*)aS + (s*8u));
            float al0 = as.x + ad.x, al1 = as.y + ad.y;
            al0 = al0 > 0.f ? al0 : NEG*al0;
            al1 = al1 > 0.f ? al1 : NEG*al1;
            float e0 = __expf(al0), e1 = __expf(al1);
            lse[wv][half][j - c0] = make_uint2(s * 160u, packh2(e0, e1));
            den0 += e0; den1 += e1;
        }
        int nn = ((n + 2) / 3) * 3;
        if (ll < nn - n) lse[wv][half][n + ll] = make_uint2(0u, 0u);
        // same-wave LDS RAW: in-order per wave, no block barrier needed
        int i = 0;
        for (; i + 9 <= nn; i += 9){     // 3 rounds of 3 edges in flight
            uint2 pa = lse[wv][half][i + gq];
            uint2 pb = lse[wv][half][i + 3 + gq];
            uint2 pc = lse[wv][half][i + 6 + gq];
            G2(pa, act ? hcvt(pa.y, sh) : 0.f);
            G2(pb, act ? hcvt(pb.y, sh) : 0.f);
            G2(pc, act ? hcvt(pc.y, sh) : 0.f);
        }
        for (; i < nn; i += 3){
            uint2 pa = lse[wv][half][i + gq];
            G2(pa, act ? hcvt(pa.y, sh) : 0.f);
        }
    }
#undef G2
    // den reduce within each half (both nodes share the 5 rounds)
    #pragma unroll
    for (int o = 1; o < 32; o <<= 1){
        den0 += __shfl_xor(den0, o, 64);
        den1 += __shfl_xor(den1, o, 64);
    }
    // fold the 3 edge-groups of each half: lanes ll<10 get g0+g1+g2.
    #pragma unroll
    for (int k = 0; k < 8; k++)
        acc[k] += __shfl(acc[k], l + 10, 64) + __shfl(acc[k], l + 20, 64);
    // lanes ll 0..9 hold totals for cols 8*ll..8*ll+7 of node d
    float r = 1.f / fmaxf((c < 5) ? den0 : den1, 1e-20f);
    #pragma unroll
    for (int k = 0; k < 8; k++) acc[k] *= r;

    // head-mean: lane ll<5 (classes 8ll..8ll+7, head0) pairs with ll+5 (head1)
    int lb = (ll < 5) ? ll : 0;
    float v[8];
    float mx = -1e30f;
    #pragma unroll
    for (int k = 0; k < 8; k++){
        float t = __shfl(acc[k], l + 5, 64);
        v[k] = 0.5f*(acc[k] + t) + rdf(b2v, 8*lb + k, isb);
        mx = fmaxf(mx, v[k]);
    }
    if (ll >= 5) mx = -1e30f;
    // log_softmax over 40 classes in lanes ll 0..4 x 8 slots (per half)
    mx = fmaxf(mx, __shfl_xor(mx, 1, 64));
    mx = fmaxf(mx, __shfl_xor(mx, 2, 64));
    mx = fmaxf(mx, __shfl_xor(mx, 4, 64));
    float ex = 0.f;
    if (ll < 5){
        #pragma unroll
        for (int k = 0; k < 8; k++) ex += __expf(v[k] - mx);
    }
    ex += __shfl_xor(ex, 1, 64);
    ex += __shfl_xor(ex, 2, 64);
    ex += __shfl_xor(ex, 4, 64);
    float lsf = __logf(ex);
    if (ll < 5){
        if (isb){
            u4v o;
            #pragma unroll
            for (int q = 0; q < 4; q++)
                o[q] = pack2(v[2*q] - mx - lsf, v[2*q+1] - mx - lsf);
            *(u4v*)((uint32_t*)out + (size_t)d*20 + 4*ll) = o;
        } else {
            float4 o0, o1;
            o0.x = v[0]-mx-lsf; o0.y = v[1]-mx-lsf; o0.z = v[2]-mx-lsf; o0.w = v[3]-mx-lsf;
            o1.x = v[4]-mx-lsf; o1.y = v[5]-mx-lsf; o1.z = v[6]-mx-lsf; o1.w = v[7]-mx-lsf;
            ((float4*)out)[(size_t)d*10 + 2*ll]     = o0;
            ((float4*)out)[(size_t)d*10 + 2*ll + 1] = o1;
        }
    }
}

extern "C" void kernel_launch(void* const* d_in, const int* in_sizes, int n_in,
                              void* d_out, int out_size, void* d_ws, size_t ws_size,
                              hipStream_t stream)
{
    const void* x    = d_in[0];
    const int*  ei   = (const int*)d_in[1];
    const void* W1   = d_in[2];
    const void* as1  = d_in[3];
    const void* ad1  = d_in[4];
    // d_in[5] = b1: cancels exactly through BatchNorm mean subtraction
    const void* gamma = d_in[6];
    const void* beta  = d_in[7];
    const void* W2   = d_in[8];
    const void* as2  = d_in[9];
    const void* ad2  = d_in[10];
    const void* b2v  = d_in[11];
    const int* esrc = ei;
    const int* edst = ei + N_EDGES;

    // --- workspace: ~76 MB total (81.7 MB proven safe) ---
    char* ws = (char*)d_ws;
    size_t off = 0;
    auto alloc = [&](size_t bytes) {
        void* p = ws + off;
        off += (bytes + 255) & ~(size_t)255;
        return p;
    };
    int*   flag  = (int*)alloc(256);
    float* stats = (float*)alloc(sizeof(float)*256);
    int*   gcur  = (int*)alloc(sizeof(int)*NBUCK);
    float* aS1   = (float*)alloc(sizeof(float)*N_NODES*2);
    float* aD1   = (float*)alloc(sizeof(float)*N_NODES*2);
    float* aS2   = (float*)alloc(sizeof(float)*N_NODES*2);
    float* aD2   = (float*)alloc(sizeof(float)*N_NODES*2);
    float* den1  = (float*)alloc(sizeof(float)*N_NODES*2);                     // 0.8 MB
    int*   deg   = (int*)alloc(sizeof(int)*N_NODES);
    int*   cur   = (int*)alloc(sizeof(int)*N_NODES);
    uint32_t* staging = (uint32_t*)alloc(sizeof(uint32_t)*(size_t)NBUCK*BCAP); // 9.6 MB (becomes wb0)
    uint32_t* wb1 = (uint32_t*)alloc(sizeof(uint32_t)*(size_t)NBUCK*BCAP);     // 9.6 MB
    unsigned short* h1  = (unsigned short*)alloc(2*(size_t)N_NODES*HID);  // 25.6 MB
    unsigned short* out1 = (unsigned short*)alloc(2*(size_t)N_NODES*HID); // 25.6 MB
    unsigned short* h2  = h1;            // alias: h1 dead after k_agg1
    uint32_t* wb0 = staging;             // alias: staging dead after k_sort

    k_init<<<1, 256, 0, stream>>>((const uint32_t*)W1, flag, gcur, stats);
    k_gemm1<<<3125, 256, 0, stream>>>(x, W1, as1, ad1, flag, h1, aS1, aD1);
    k_bin<<<NBB, 256, 0, stream>>>(esrc, edst, gcur, staging);
    k_sort<<<NBUCK, 256, 0, stream>>>(gcur, staging, aS1, aD1, deg, cur,
                                      wb1, den1);
    k_agg1<<<100000, 256, 0, stream>>>(cur, deg, wb0, wb1, den1,
                                       (const uint32_t*)h1, (uint32_t*)out1);
    k_bnstats<<<128, 256, 0, stream>>>((const uint32_t*)out1, stats);
    k_gemm2<<<1563, 256, 0, stream>>>(out1, stats, gamma, beta, W2, as2, ad2,
                                      flag, h2, aS2, aD2);
    k_agg2<<<12500, 256, 0, stream>>>(cur, deg, wb0, aS2, aD2,
                                      (const uint32_t*)h2, b2v, flag, d_out);
}

// Round 7
// 544.165 us; speedup vs baseline: 1.0226x; 1.0226x over previous
//
#include <hip/hip_runtime.h>
#include <hip/hip_bf16.h>
#include <hip/hip_fp16.h>
#include <stdint.h>

#define N_NODES 100000
#define N_EDGES 1600000
#define ET (N_EDGES + N_NODES)   // edges + self-loops
#define HID 128
#define C2 40
#define F2 80
#define NEG 0.2f
#define BN_EPS 1e-5f
#define NBUCK 391                // ceil(100000/256) coarse buckets (256 nodes each)
#define BCAP 6144                // slots per bucket (mean 4608, sd 66 -> +23 sigma)
#define NBB 640                  // bin-pass blocks
#define EPB ((ET + NBB - 1) / NBB)
#define CH2 256                  // per-NODE LDS edge cache in k_agg2

typedef __hip_bfloat16 bf16;
typedef __attribute__((ext_vector_type(8))) short s8v;          // 8 bf16 MFMA A/B frag
typedef __attribute__((ext_vector_type(4))) float f4v;          // MFMA C/D frag
typedef __attribute__((ext_vector_type(4))) unsigned int u4v;
typedef __attribute__((ext_vector_type(2))) unsigned int u2v;

__device__ __forceinline__ float b2f(bf16 v){ return __bfloat162float(v); }
__device__ __forceinline__ float rdf(const void* p, size_t i, int isb){
    return isb ? b2f(((const bf16*)p)[i]) : ((const float*)p)[i];
}
__device__ __forceinline__ unsigned short f2bb(float v){
    bf16 h = __float2bfloat16(v);
    return *(unsigned short*)&h;
}
__device__ __forceinline__ uint32_t pack2(float a, float b){
    return (uint32_t)f2bb(a) | ((uint32_t)f2bb(b) << 16);
}
__device__ __forceinline__ uint32_t packh2(float a, float b){
    return (uint32_t)__half_as_ushort(__float2half(a))
         | ((uint32_t)__half_as_ushort(__float2half(b)) << 16);
}
__device__ __forceinline__ float lo16(uint32_t u){ return __uint_as_float(u << 16); }
__device__ __forceinline__ float hi16(uint32_t u){ return __uint_as_float(u & 0xFFFF0000u); }
__device__ __forceinline__ float hcvt(uint32_t w, int sh){
    return __half2float(__ushort_as_half((unsigned short)((w >> sh) & 0xFFFFu)));
}
// decode 15-bit (sign-stripped half) weight from a (src<<15)|w15 record
__device__ __forceinline__ float w15f(uint32_t w){
    return __half2float(__ushort_as_half((unsigned short)(w & 0x7FFFu)));
}

// ---------------- init: dtype flag + zero gcur/stats ------------------------
__global__ __launch_bounds__(256) void k_init(
    const uint32_t* __restrict__ w1bits, int* __restrict__ flag,
    int* __restrict__ gcur, float* __restrict__ stats)
{
    __shared__ int cnt;
    int t = threadIdx.x;
    if (t == 0) cnt = 0;
    __syncthreads();
    uint32_t b = w1bits[t];
    float lo = __uint_as_float((b & 0xFFFFu) << 16);
    float a = fabsf(lo);
    if (a > 1e-8f && a < 1.0f) atomicAdd(&cnt, 1);
    for (int i = t; i < NBUCK; i += 256) gcur[i] = 0;
    stats[t] = 0.f;
    __syncthreads();
    if (t == 0) *flag = (cnt >= 192) ? 1 : 0;
}

// ---------------- GEMM1 (MFMA): h1 = x @ W1, + fused att1 dots --------------
// h1 is written SLICE-MAJOR: region k (k = col/16, 8 regions of 3.2 MB each)
// holds rows' k-th 16-col slice contiguously: h1[k*N*16 + row*16 + (col&15)].
// Within a (ct, quad-row) store the 16 lanes still write 32 contiguous bytes.
__global__ __launch_bounds__(256) void k_gemm1(
    const void* __restrict__ x, const void* __restrict__ W1,
    const void* __restrict__ attS, const void* __restrict__ attD,
    const int* __restrict__ flag, unsigned short* __restrict__ h1,
    float* __restrict__ aS, float* __restrict__ aD)
{
    __shared__ __attribute__((aligned(16))) unsigned short wT[128*132]; // 33.8 KB
    const int isb = *flag;
    const int tid = threadIdx.x;
    if (isb) {
        const unsigned short* w = (const unsigned short*)W1;
        for (int idx = tid; idx < 128*128; idx += 256){
            int k = idx >> 7, n = idx & 127;
            wT[n*132 + k] = w[idx];
        }
    } else {
        const float* w = (const float*)W1;
        for (int idx = tid; idx < 128*128; idx += 256){
            int k = idx >> 7, n = idx & 127;
            wT[n*132 + k] = f2bb(w[idx]);
        }
    }
    __syncthreads();

    const int w4 = tid >> 6, lane = tid & 63, quad = lane >> 4, l16 = lane & 15;
    const int rowbase = blockIdx.x*32 + (w4 >> 1)*16;   // 3125*32 = 100000 exact
    const int colbase = (w4 & 1)*64;
    const int head = w4 & 1;

    s8v bfr[4][4];
    float asv[4], adv[4];
    #pragma unroll
    for (int ct = 0; ct < 4; ct++){
        int n = colbase + ct*16 + l16;
        asv[ct] = rdf(attS, n, isb);
        adv[ct] = rdf(attD, n, isb);
        #pragma unroll
        for (int s = 0; s < 4; s++){
            int k0 = s*32 + quad*8;
            const unsigned short* p = &wT[n*132 + k0];
            u2v a = *(const u2v*)p, b = *(const u2v*)(p+4);
            union { u4v u; s8v s; } cv; cv.u = (u4v){a[0],a[1],b[0],b[1]};
            bfr[ct][s] = cv.s;
        }
    }

    f4v acc[4];
    #pragma unroll
    for (int ct = 0; ct < 4; ct++) acc[ct] = (f4v){0.f,0.f,0.f,0.f};

    const int m = rowbase + l16;
    #pragma unroll
    for (int s = 0; s < 4; s++){
        int k0 = s*32 + quad*8;
        s8v af;
        if (isb){
            union { u4v u; s8v s; } cv;
            cv.u = *(const u4v*)((const unsigned short*)x + (size_t)m*128 + k0);
            af = cv.s;
        } else {
            const float* xp = (const float*)x + (size_t)m*128 + k0;
            f4v f0 = *(const f4v*)xp, f1 = *(const f4v*)(xp+4);
            union { u4v u; s8v s; } cv;
            cv.u = (u4v){pack2(f0[0],f0[1]), pack2(f0[2],f0[3]),
                         pack2(f1[0],f1[1]), pack2(f1[2],f1[3])};
            af = cv.s;
        }
        #pragma unroll
        for (int ct = 0; ct < 4; ct++)
            acc[ct] = __builtin_amdgcn_mfma_f32_16x16x32_bf16(af, bfr[ct][s], acc[ct], 0,0,0);
    }

    // C/D: col = lane&15, row = quad*4 + reg  -> slice-major store
    #pragma unroll
    for (int ct = 0; ct < 4; ct++){
        int col = colbase + ct*16 + l16;
        int slc = col >> 4;
        #pragma unroll
        for (int r = 0; r < 4; r++){
            int row = rowbase + quad*4 + r;
            h1[(size_t)slc*(N_NODES*16) + (size_t)row*16 + (col & 15)]
                = f2bb(acc[ct][r]);
        }
    }

    // fused att1: per row, reduce acc*att over wave's 64 cols (one head).
    #pragma unroll
    for (int r = 0; r < 4; r++){
        float vs = 0.f, vd = 0.f;
        #pragma unroll
        for (int ct = 0; ct < 4; ct++){ vs += acc[ct][r]*asv[ct]; vd += acc[ct][r]*adv[ct]; }
        #pragma unroll
        for (int o = 1; o < 16; o <<= 1){
            vs += __shfl_xor(vs, o, 64);
            vd += __shfl_xor(vd, o, 64);
        }
        if (l16 == 0){
            int row = rowbase + quad*4 + r;
            aS[row*2 + head] = vs;
            aD[row*2 + head] = vd;
        }
    }
}

// ---------------- CSR pass 1: LDS-binned coarse scatter ---------------------
__global__ __launch_bounds__(256) void k_bin(
    const int* __restrict__ esrc, const int* __restrict__ edst,
    int* __restrict__ gcur, uint32_t* __restrict__ staging)
{
    __shared__ int cnt[NBUCK];
    __shared__ int bb[NBUCK];
    const int t = threadIdx.x;
    for (int i = t; i < NBUCK; i += 256) cnt[i] = 0;
    __syncthreads();
    const int e0 = blockIdx.x * EPB;
    const int e1 = (e0 + EPB < ET) ? e0 + EPB : ET;
    for (int e = e0 + t; e < e1; e += 256){
        int d = (e < N_EDGES) ? edst[e] : e - N_EDGES;
        atomicAdd(&cnt[d >> 8], 1);
    }
    __syncthreads();
    // rotate flush order by block to avoid lockstep per-address atomic chains
    const int bofs = (int)(blockIdx.x % NBUCK);
    for (int i = t; i < NBUCK; i += 256){
        int bkt = i + bofs; if (bkt >= NBUCK) bkt -= NBUCK;
        int c = cnt[bkt];
        bb[bkt] = c ? atomicAdd(&gcur[bkt], c) : 0;
        cnt[bkt] = 0;
    }
    __syncthreads();
    for (int e = e0 + t; e < e1; e += 256){
        int d, s;
        if (e < N_EDGES){ s = esrc[e]; d = edst[e]; } else { s = d = e - N_EDGES; }
        int b = d >> 8;
        int r = atomicAdd(&cnt[b], 1);
        int p = bb[b] + r;
        if (p < BCAP) staging[(size_t)b*BCAP + p] = ((uint32_t)s << 8) | (uint32_t)(d & 255);
    }
}

// ---------------- CSR pass 2: counting sort + fused layer-1 weights ---------
// Sort keeps (src<<8)|dl per slot. The weight phase is EDGE-PARALLEL and
// coalesced: per-bucket aD is LDS-cached, denominators accumulate via LDS
// float atomics, and the two 4B records per slot are written with stride-256
// coalesced stores:
//   wb0[slot] = (src<<15) | half_bits(exp_h0)   (half has no sign bit: exact)
//   wb1[slot] = (src<<15) | half_bits(exp_h1)
// wb0 reuses the staging buffer (all staging reads complete before overwrite).
__global__ __launch_bounds__(256) void k_sort(
    const int* __restrict__ gcur, uint32_t* stg /* in: staging, out: wb0 */,
    const float* __restrict__ aS, const float* __restrict__ aD,
    int* __restrict__ deg, int* __restrict__ cur,
    uint32_t* __restrict__ wb1, float* __restrict__ den)
{
    __shared__ int h[256], sc[256], rk[256];
    __shared__ int lsrc[BCAP];
    __shared__ float ad0s[256], ad1s[256], dn0[256], dn1[256];
    const int b = blockIdx.x;
    const int t = threadIdx.x;
    const int base = b * BCAP;
    int cnt = gcur[b];
    if (cnt > BCAP) cnt = BCAP;
    h[t] = 0; rk[t] = 0; dn0[t] = 0.f; dn1[t] = 0.f;
    int dg = b*256 + t;
    if (dg < N_NODES){
        float2 a = *(const float2*)(aD + (size_t)dg*2);
        ad0s[t] = a.x; ad1s[t] = a.y;
    }
    __syncthreads();
    for (int i = t; i < cnt; i += 256)
        atomicAdd(&h[stg[base + i] & 255u], 1);
    __syncthreads();
    sc[t] = h[t];
    __syncthreads();
    for (int off = 1; off < 256; off <<= 1){
        int v = (t >= off) ? sc[t - off] : 0;
        __syncthreads();
        sc[t] += v;
        __syncthreads();
    }
    if (dg < N_NODES){
        deg[dg] = h[t];
        cur[dg] = base + sc[t];    // end pointer; start = end - deg
    }
    __syncthreads();
    for (int i = t; i < cnt; i += 256){
        uint32_t w = stg[base + i];
        int dl = w & 255u;
        int r = atomicAdd(&rk[dl], 1);
        lsrc[sc[dl] - h[dl] + r] = (int)w & ~255 | dl;   // (src<<8)|dl, sorted
    }
    __syncthreads();
    // ---- edge-parallel weight phase (coalesced reads/writes) ----
    for (int i = t; i < cnt; i += 256){
        uint32_t w = (uint32_t)lsrc[i];
        uint32_t s = w >> 8;
        int dl = (int)(w & 255u);
        float2 as = *(const float2*)(aS + (size_t)s*2);
        float al0 = as.x + ad0s[dl], al1 = as.y + ad1s[dl];
        al0 = al0 > 0.f ? al0 : NEG*al0;
        al1 = al1 > 0.f ? al1 : NEG*al1;
        float e0 = __expf(al0), e1 = __expf(al1);
        atomicAdd(&dn0[dl], e0);
        atomicAdd(&dn1[dl], e1);
        uint32_t sb = s << 15;
        uint32_t p0 = (uint32_t)__half_as_ushort(__float2half(e0)) & 0x7FFFu;
        uint32_t p1 = (uint32_t)__half_as_ushort(__float2half(e1)) & 0x7FFFu;
        stg[base + i] = sb | p0;   // wb0
        wb1[base + i] = sb | p1;
    }
    __syncthreads();
    if (dg < N_NODES){
        den[(size_t)dg*2]     = dn0[t];
        den[(size_t)dg*2 + 1] = dn1[t];
    }
}

// ---------------- layer-1 agg: slice-major 8-way XCD split ------------------
// h1 region k (contiguous 3.2 MB) = rows' k-th 16-col slice. Task = (node,
// slice) with slice = blockIdx&7: under round-robin block->XCD mapping each
// XCD's gathers land in ONE 3.2 MB range < 4 MB L2 -> resident after warm-up,
// FETCH ~= compulsory. No exp/phase-1 here (precomputed wb records), no LDS.
// Per half-wave task: 2 lanes/edge x dwordx4 from the region, 16 edges/round,
// 2 rounds in flight; invalid slots clamp to 'start' (L2-hot, coalesced).
__global__ __launch_bounds__(256) void k_agg1(
    const int* __restrict__ cur, const int* __restrict__ deg,
    const uint32_t* __restrict__ wb0, const uint32_t* __restrict__ wb1,
    const float* __restrict__ den, const uint32_t* __restrict__ h1u,
    uint32_t* __restrict__ out1u)
{
    const int bx = blockIdx.x;
    const int k = bx & 7;                // slice class -> XCD affinity
    const int grp = bx >> 3;             // 12500 groups x 8 nodes
    const int h = k >> 2;                // head: slices 0-3 h0, 4-7 h1
    const uint32_t* __restrict__ wb = h ? wb1 : wb0;
    const int wv = threadIdx.x >> 6;
    const int l = threadIdx.x & 63;
    const int half = l >> 5, ll = l & 31;
    const int d = grp*8 + wv*2 + half;   // < 100000 exact
    const int sub = ll & 1, epair = ll >> 1;
    const char* hb = (const char*)h1u + (size_t)k*(N_NODES*32) + sub*16;
    int end = cur[d];
    int dgv = deg[d];
    int start = end - dgv;
    float dh = den[(size_t)d*2 + h];
    float acc[8];
    #pragma unroll
    for (int q = 0; q < 8; q++) acc[q] = 0.f;
    int rm = (dgv + 15) >> 4;
    rm = max(rm, __shfl_xor(rm, 32, 64));   // uniform trip count per wave

#define GF(G, W) { float Wf = (W); \
    acc[0] += Wf*lo16((G)[0]); acc[1] += Wf*hi16((G)[0]); \
    acc[2] += Wf*lo16((G)[1]); acc[3] += Wf*hi16((G)[1]); \
    acc[4] += Wf*lo16((G)[2]); acc[5] += Wf*hi16((G)[2]); \
    acc[6] += Wf*lo16((G)[3]); acc[7] += Wf*hi16((G)[3]); }

    int t = 0;
    for (; t + 2 <= rm; t += 2){         // 32 edges, 2 gathers/lane in flight
        int j0 = start + (t << 4) + epair;
        int j1 = j0 + 16;
        bool v0 = j0 < end, v1 = j1 < end;
        uint32_t w0 = __builtin_nontemporal_load(wb + (v0 ? j0 : start));
        uint32_t w1 = __builtin_nontemporal_load(wb + (v1 ? j1 : start));
        u4v G0 = *(const u4v*)(hb + ((size_t)(w0 >> 15) << 5));
        u4v G1 = *(const u4v*)(hb + ((size_t)(w1 >> 15) << 5));
        float f0 = v0 ? w15f(w0) : 0.f;
        float f1 = v1 ? w15f(w1) : 0.f;
        GF(G0, f0);
        GF(G1, f1);
    }
    if (t < rm){
        int j0 = start + (t << 4) + epair;
        bool v0 = j0 < end;
        uint32_t w0 = __builtin_nontemporal_load(wb + (v0 ? j0 : start));
        u4v G0 = *(const u4v*)(hb + ((size_t)(w0 >> 15) << 5));
        float f0 = v0 ? w15f(w0) : 0.f;
        GF(G0, f0);
    }
#undef GF
    // fold 16 edge-pairs onto the 2 sub-lanes of each half
    #pragma unroll
    for (int q = 0; q < 8; q++){
        acc[q] += __shfl_xor(acc[q], 2, 64);
        acc[q] += __shfl_xor(acc[q], 4, 64);
        acc[q] += __shfl_xor(acc[q], 8, 64);
        acc[q] += __shfl_xor(acc[q], 16, 64);
    }
    if (ll < 2){
        float rr = 1.f / fmaxf(dh, 1e-20f);
        u4v o;
        #pragma unroll
        for (int q = 0; q < 4; q++) o[q] = pack2(acc[2*q]*rr, acc[2*q+1]*rr);
        __builtin_nontemporal_store(o,
            (u4v*)(out1u + (size_t)d*64 + 8*k + 4*ll));
    }
}

// ---------------- BatchNorm stats: per-block LDS reduce, then 1 atomic ------
__global__ __launch_bounds__(256) void k_bnstats(
    const uint32_t* __restrict__ out1u, float* __restrict__ stats)
{
    __shared__ float red[4][64][4];      // wave x feat-pair x {s0,s1,q0,q1} = 4 KB
    int fp = threadIdx.x & 63;
    int wv = threadIdx.x >> 6;
    float s0 = 0.f, q0 = 0.f, s1 = 0.f, q1 = 0.f;
    for (int r = blockIdx.x*4 + wv; r < N_NODES; r += 512){
        uint32_t u = out1u[(size_t)r*64 + fp];
        float f0 = lo16(u), f1 = hi16(u);
        s0 += f0; q0 += f0*f0; s1 += f1; q1 += f1*f1;
    }
    red[wv][fp][0] = s0; red[wv][fp][1] = s1;
    red[wv][fp][2] = q0; red[wv][fp][3] = q1;
    __syncthreads();
    if (threadIdx.x < 64){
        int l = threadIdx.x;
        float a0=0.f, a1=0.f, b0=0.f, b1=0.f;
        #pragma unroll
        for (int w = 0; w < 4; w++){
            a0 += red[w][l][0]; a1 += red[w][l][1];
            b0 += red[w][l][2]; b1 += red[w][l][3];
        }
        unsafeAtomicAdd(&stats[2*l],       a0);
        unsafeAtomicAdd(&stats[2*l+1],     a1);
        unsafeAtomicAdd(&stats[128+2*l],   b0);
        unsafeAtomicAdd(&stats[128+2*l+1], b1);
    }
}

// ---------------- GEMM2 (MFMA): h2 = BN(out1) @ W2, + fused att2, BN-fin ----
__global__ __launch_bounds__(256) void k_gemm2(
    const unsigned short* __restrict__ out1b, const float* __restrict__ stats,
    const void* __restrict__ gamma, const void* __restrict__ beta,
    const void* __restrict__ W2, const void* __restrict__ attS,
    const void* __restrict__ attD, const int* __restrict__ flag,
    unsigned short* __restrict__ h2, float* __restrict__ aS, float* __restrict__ aD)
{
    __shared__ __attribute__((aligned(16))) unsigned short wT[80*132]; // 21.1 KB
    __shared__ float scl[128], shl[128];
    const int isb = *flag;
    const int tid = threadIdx.x;
    for (int idx = tid; idx < 128*80; idx += 256){
        int k = idx / 80, n = idx - k*80;
        wT[n*132 + k] = isb ? ((const unsigned short*)W2)[idx]
                            : f2bb(((const float*)W2)[idx]);
    }
    if (tid < 128){   // inline BN finalize
        float mean = stats[tid] * (1.f / N_NODES);
        float var = fmaxf(stats[128+tid] * (1.f / N_NODES) - mean*mean, 0.f);
        float rs = rsqrtf(var + BN_EPS);
        float sc = rdf(gamma, tid, isb) * rs;
        scl[tid] = sc;
        shl[tid] = rdf(beta, tid, isb) - mean*sc;
    }
    __syncthreads();

    const int w4 = tid >> 6, lane = tid & 63, quad = lane >> 4, l16 = lane & 15;
    const int rowbase = blockIdx.x*64 + w4*16;

    s8v bfr[5][4];
    float asv[5], adv[5];
    #pragma unroll
    for (int ct = 0; ct < 5; ct++){
        int n = ct*16 + l16;
        asv[ct] = rdf(attS, n, isb);
        adv[ct] = rdf(attD, n, isb);
        #pragma unroll
        for (int s = 0; s < 4; s++){
            int k0 = s*32 + quad*8;
            const unsigned short* p = &wT[n*132 + k0];
            u2v a = *(const u2v*)p, b = *(const u2v*)(p+4);
            union { u4v u; s8v s; } cv; cv.u = (u4v){a[0],a[1],b[0],b[1]};
            bfr[ct][s] = cv.s;
        }
    }

    f4v acc[5];
    #pragma unroll
    for (int ct = 0; ct < 5; ct++) acc[ct] = (f4v){0.f,0.f,0.f,0.f};

    int m = rowbase + l16;
    int mc = m < N_NODES ? m : N_NODES - 1;
    #pragma unroll
    for (int s = 0; s < 4; s++){
        int k0 = s*32 + quad*8;
        union { u4v u; s8v s8; } cin;
        cin.u = *(const u4v*)(out1b + (size_t)mc*128 + k0);
        u4v up;
        #pragma unroll
        for (int i = 0; i < 4; i++){
            float f0 = lo16(cin.u[i]), f1 = hi16(cin.u[i]);
            int k = k0 + 2*i;
            up[i] = pack2(f0*scl[k] + shl[k], f1*scl[k+1] + shl[k+1]);
        }
        union { u4v u; s8v s8; } cv; cv.u = up;
        #pragma unroll
        for (int ct = 0; ct < 5; ct++)
            acc[ct] = __builtin_amdgcn_mfma_f32_16x16x32_bf16(cv.s8, bfr[ct][s], acc[ct], 0,0,0);
    }

    #pragma unroll
    for (int ct = 0; ct < 5; ct++){
        int col = ct*16 + l16;
        #pragma unroll
        for (int r = 0; r < 4; r++){
            int row = rowbase + quad*4 + r;
            if (row < N_NODES) h2[(size_t)row*80 + col] = f2bb(acc[ct][r]);
        }
    }

    // fused att2: head0 = cols 0..39, head1 = cols 40..79.
    #pragma unroll
    for (int r = 0; r < 4; r++){
        float vs0 = 0.f, vs1 = 0.f, vd0 = 0.f, vd1 = 0.f;
        #pragma unroll
        for (int ct = 0; ct < 5; ct++){
            int col = ct*16 + l16;
            float ps = acc[ct][r]*asv[ct], pd = acc[ct][r]*adv[ct];
            if (col < 40){ vs0 += ps; vd0 += pd; } else { vs1 += ps; vd1 += pd; }
        }
        #pragma unroll
        for (int o = 1; o < 16; o <<= 1){
            vs0 += __shfl_xor(vs0, o, 64); vs1 += __shfl_xor(vs1, o, 64);
            vd0 += __shfl_xor(vd0, o, 64); vd1 += __shfl_xor(vd1, o, 64);
        }
        if (l16 == 0){
            int row = rowbase + quad*4 + r;
            if (row < N_NODES){
                aS[row*2 + 0] = vs0; aS[row*2 + 1] = vs1;
                aD[row*2 + 0] = vd0; aD[row*2 + 1] = vd1;
            }
        }
    }
}

// ---------------- layer-2 agg: 2 nodes/wave, 10 lanes/edge x dwordx4 --------
// (R3 form — best measured.) src decoded from wb0 records (w >> 15).
__global__ __launch_bounds__(256) void k_agg2(
    const int* __restrict__ cur, const int* __restrict__ deg,
    const uint32_t* __restrict__ wb0, const float* __restrict__ aS,
    const float* __restrict__ aD, const uint32_t* __restrict__ h2u,
    const void* __restrict__ b2v, const int* __restrict__ flag,
    void* __restrict__ out)
{
    __shared__ uint2 lse[4][2][CH2 + 4];   // 16.6 KB
    const int wv = threadIdx.x >> 6;
    const int l = threadIdx.x & 63;
    const int half = l >> 5, ll = l & 31;
    const int d = blockIdx.x*8 + wv*2 + half;   // 12500*8 = 100000 exact
    const int isb = *flag;
    const int c = ll % 10;               // feature slot within edge
    const int g = ll / 10;               // edge group 0..2 (3 = idle lanes)
    const bool act = ll < 30;
    const int gq = act ? g : 0;          // safe lse index for idle lanes
    const uint32_t c16 = (uint32_t)(c*16);
    int end   = cur[d];
    int start = end - deg[d];
    float2 ad = *(const float2*)(aD + d*2);
    const int sh = (c >= 5) ? 16 : 0;    // cols 8c..8c+7: head1 iff 8c >= 40
    float den0 = 0.f, den1 = 0.f;
    float acc[8];
    #pragma unroll
    for (int k = 0; k < 8; k++) acc[k] = 0.f;
    const char* hb = (const char*)h2u;

#define G2(P, W) { u4v Gx = *(const u4v*)(hb + ((P).x + c16)); \
    float Wf = (W); \
    acc[0] += Wf*lo16(Gx[0]); acc[1] += Wf*hi16(Gx[0]); \
    acc[2] += Wf*lo16(Gx[1]); acc[3] += Wf*hi16(Gx[1]); \
    acc[4] += Wf*lo16(Gx[2]); acc[5] += Wf*hi16(Gx[2]); \
    acc[6] += Wf*lo16(Gx[3]); acc[7] += Wf*hi16(Gx[3]); }

    for (int c0 = start; c0 < end; c0 += CH2){
        int c1 = (c0 + CH2 < end) ? c0 + CH2 : end;
        int n = c1 - c0;
        // phase 1: half's 32 lanes parallel over this node's edges
        for (int j = c0 + ll; j < c1; j += 32){
            uint32_t s = __builtin_nontemporal_load(wb0 + j) >> 15;
            float2 as = *(const float2*)((const char*)aS + (s*8u));
            float al0 = as.x + ad.x, al1 = as.y + ad.y;
            al0 = al0 > 0.f ? al0 : NEG*al0;
            al1 = al1 > 0.f ? al1 : NEG*al1;
            float e0 = __expf(al0), e1 = __expf(al1);
            lse[wv][half][j - c0] = make_uint2(s * 160u, packh2(e0, e1));
            den0 += e0; den1 += e1;
        }
        int nn = ((n + 2) / 3) * 3;
        if (ll < nn - n) lse[wv][half][n + ll] = make_uint2(0u, 0u);
        // same-wave LDS RAW: in-order per wave, no block barrier needed
        int i = 0;
        for (; i + 9 <= nn; i += 9){     // 3 rounds of 3 edges in flight
            uint2 pa = lse[wv][half][i + gq];
            uint2 pb = lse[wv][half][i + 3 + gq];
            uint2 pc = lse[wv][half][i + 6 + gq];
            G2(pa, act ? hcvt(pa.y, sh) : 0.f);
            G2(pb, act ? hcvt(pb.y, sh) : 0.f);
            G2(pc, act ? hcvt(pc.y, sh) : 0.f);
        }
        for (; i < nn; i += 3){
            uint2 pa = lse[wv][half][i + gq];
            G2(pa, act ? hcvt(pa.y, sh) : 0.f);
        }
    }
#undef G2
    // den reduce within each half (both nodes share the 5 rounds)
    #pragma unroll
    for (int o = 1; o < 32; o <<= 1){
        den0 += __shfl_xor(den0, o, 64);
        den1 += __shfl_xor(den1, o, 64);
    }
    // fold the 3 edge-groups of each half: lanes ll<10 get g0+g1+g2.
    #pragma unroll
    for (int k = 0; k < 8; k++)
        acc[k] += __shfl(acc[k], l + 10, 64) + __shfl(acc[k], l + 20, 64);
    // lanes ll 0..9 hold totals for cols 8*ll..8*ll+7 of node d
    float r = 1.f / fmaxf((c < 5) ? den0 : den1, 1e-20f);
    #pragma unroll
    for (int k = 0; k < 8; k++) acc[k] *= r;

    // head-mean: lane ll<5 (classes 8ll..8ll+7, head0) pairs with ll+5 (head1)
    int lb = (ll < 5) ? ll : 0;
    float v[8];
    float mx = -1e30f;
    #pragma unroll
    for (int k = 0; k < 8; k++){
        float t = __shfl(acc[k], l + 5, 64);
        v[k] = 0.5f*(acc[k] + t) + rdf(b2v, 8*lb + k, isb);
        mx = fmaxf(mx, v[k]);
    }
    if (ll >= 5) mx = -1e30f;
    // log_softmax over 40 classes in lanes ll 0..4 x 8 slots (per half)
    mx = fmaxf(mx, __shfl_xor(mx, 1, 64));
    mx = fmaxf(mx, __shfl_xor(mx, 2, 64));
    mx = fmaxf(mx, __shfl_xor(mx, 4, 64));
    float ex = 0.f;
    if (ll < 5){
        #pragma unroll
        for (int k = 0; k < 8; k++) ex += __expf(v[k] - mx);
    }
    ex += __shfl_xor(ex, 1, 64);
    ex += __shfl_xor(ex, 2, 64);
    ex += __shfl_xor(ex, 4, 64);
    float lsf = __logf(ex);
    if (ll < 5){
        if (isb){
            u4v o;
            #pragma unroll
            for (int q = 0; q < 4; q++)
                o[q] = pack2(v[2*q] - mx - lsf, v[2*q+1] - mx - lsf);
            *(u4v*)((uint32_t*)out + (size_t)d*20 + 4*ll) = o;
        } else {
            float4 o0, o1;
            o0.x = v[0]-mx-lsf; o0.y = v[1]-mx-lsf; o0.z = v[2]-mx-lsf; o0.w = v[3]-mx-lsf;
            o1.x = v[4]-mx-lsf; o1.y = v[5]-mx-lsf; o1.z = v[6]-mx-lsf; o1.w = v[7]-mx-lsf;
            ((float4*)out)[(size_t)d*10 + 2*ll]     = o0;
            ((float4*)out)[(size_t)d*10 + 2*ll + 1] = o1;
        }
    }
}

extern "C" void kernel_launch(void* const* d_in, const int* in_sizes, int n_in,
                              void* d_out, int out_size, void* d_ws, size_t ws_size,
                              hipStream_t stream)
{
    const void* x    = d_in[0];
    const int*  ei   = (const int*)d_in[1];
    const void* W1   = d_in[2];
    const void* as1  = d_in[3];
    const void* ad1  = d_in[4];
    // d_in[5] = b1: cancels exactly through BatchNorm mean subtraction
    const void* gamma = d_in[6];
    const void* beta  = d_in[7];
    const void* W2   = d_in[8];
    const void* as2  = d_in[9];
    const void* ad2  = d_in[10];
    const void* b2v  = d_in[11];
    const int* esrc = ei;
    const int* edst = ei + N_EDGES;

    // --- workspace: ~76 MB total (81.7 MB proven safe) ---
    char* ws = (char*)d_ws;
    size_t off = 0;
    auto alloc = [&](size_t bytes) {
        void* p = ws + off;
        off += (bytes + 255) & ~(size_t)255;
        return p;
    };
    int*   flag  = (int*)alloc(256);
    float* stats = (float*)alloc(sizeof(float)*256);
    int*   gcur  = (int*)alloc(sizeof(int)*NBUCK);
    float* aS1   = (float*)alloc(sizeof(float)*N_NODES*2);
    float* aD1   = (float*)alloc(sizeof(float)*N_NODES*2);
    float* aS2   = (float*)alloc(sizeof(float)*N_NODES*2);
    float* aD2   = (float*)alloc(sizeof(float)*N_NODES*2);
    float* den1  = (float*)alloc(sizeof(float)*N_NODES*2);                     // 0.8 MB
    int*   deg   = (int*)alloc(sizeof(int)*N_NODES);
    int*   cur   = (int*)alloc(sizeof(int)*N_NODES);
    uint32_t* staging = (uint32_t*)alloc(sizeof(uint32_t)*(size_t)NBUCK*BCAP); // 9.6 MB (becomes wb0)
    uint32_t* wb1 = (uint32_t*)alloc(sizeof(uint32_t)*(size_t)NBUCK*BCAP);     // 9.6 MB
    unsigned short* h1  = (unsigned short*)alloc(2*(size_t)N_NODES*HID);  // 25.6 MB
    unsigned short* out1 = (unsigned short*)alloc(2*(size_t)N_NODES*HID); // 25.6 MB
    unsigned short* h2  = h1;            // alias: h1 dead after k_agg1
    uint32_t* wb0 = staging;             // alias: staging dead after k_sort

    k_init<<<1, 256, 0, stream>>>((const uint32_t*)W1, flag, gcur, stats);
    k_gemm1<<<3125, 256, 0, stream>>>(x, W1, as1, ad1, flag, h1, aS1, aD1);
    k_bin<<<NBB, 256, 0, stream>>>(esrc, edst, gcur, staging);
    k_sort<<<NBUCK, 256, 0, stream>>>(gcur, staging, aS1, aD1, deg, cur,
                                      wb1, den1);
    k_agg1<<<100000, 256, 0, stream>>>(cur, deg, wb0, wb1, den1,
                                       (const uint32_t*)h1, (uint32_t*)out1);
    k_bnstats<<<128, 256, 0, stream>>>((const uint32_t*)out1, stats);
    k_gemm2<<<1563, 256, 0, stream>>>(out1, stats, gamma, beta, W2, as2, ad2,
                                      flag, h2, aS2, aD2);
    k_agg2<<<12500, 256, 0, stream>>>(cur, deg, wb0, aS2, aD2,
                                      (const uint32_t*)h2, b2v, flag, d_out);
}

// Round 8
// 526.183 us; speedup vs baseline: 1.0576x; 1.0342x over previous
//
#include <hip/hip_runtime.h>
#include <hip/hip_bf16.h>
#include <hip/hip_fp16.h>
#include <stdint.h>

#define N_NODES 100000
#define N_EDGES 1600000
#define ET (N_EDGES + N_NODES)   // edges + self-loops
#define HID 128
#define C2 40
#define F2 80
#define NEG 0.2f
#define BN_EPS 1e-5f
#define NBUCK 391                // ceil(100000/256) coarse buckets (256 nodes each)
#define BCAP 6144                // slots per bucket (mean 4608, sd 66 -> +23 sigma)
#define NBB 640                  // bin-pass blocks
#define EPB ((ET + NBB - 1) / NBB)
#define CH2 256                  // per-NODE LDS edge cache in k_agg2

typedef __hip_bfloat16 bf16;
typedef __attribute__((ext_vector_type(8))) short s8v;          // 8 bf16 MFMA A/B frag
typedef __attribute__((ext_vector_type(4))) float f4v;          // MFMA C/D frag
typedef __attribute__((ext_vector_type(4))) unsigned int u4v;
typedef __attribute__((ext_vector_type(2))) unsigned int u2v;

__device__ __forceinline__ float b2f(bf16 v){ return __bfloat162float(v); }
__device__ __forceinline__ float rdf(const void* p, size_t i, int isb){
    return isb ? b2f(((const bf16*)p)[i]) : ((const float*)p)[i];
}
__device__ __forceinline__ unsigned short f2bb(float v){
    bf16 h = __float2bfloat16(v);
    return *(unsigned short*)&h;
}
__device__ __forceinline__ uint32_t pack2(float a, float b){
    return (uint32_t)f2bb(a) | ((uint32_t)f2bb(b) << 16);
}
__device__ __forceinline__ uint32_t packh2(float a, float b){
    return (uint32_t)__half_as_ushort(__float2half(a))
         | ((uint32_t)__half_as_ushort(__float2half(b)) << 16);
}
__device__ __forceinline__ float lo16(uint32_t u){ return __uint_as_float(u << 16); }
__device__ __forceinline__ float hi16(uint32_t u){ return __uint_as_float(u & 0xFFFF0000u); }
__device__ __forceinline__ float hcvt(uint32_t w, int sh){
    return __half2float(__ushort_as_half((unsigned short)((w >> sh) & 0xFFFFu)));
}
// decode 15-bit (sign-stripped half) weight from a (src<<15)|w15 record
__device__ __forceinline__ float w15f(uint32_t w){
    return __half2float(__ushort_as_half((unsigned short)(w & 0x7FFFu)));
}

// ---------------- init: dtype flag + zero gcur/stats ------------------------
__global__ __launch_bounds__(256) void k_init(
    const uint32_t* __restrict__ w1bits, int* __restrict__ flag,
    int* __restrict__ gcur, float* __restrict__ stats)
{
    __shared__ int cnt;
    int t = threadIdx.x;
    if (t == 0) cnt = 0;
    __syncthreads();
    uint32_t b = w1bits[t];
    float lo = __uint_as_float((b & 0xFFFFu) << 16);
    float a = fabsf(lo);
    if (a > 1e-8f && a < 1.0f) atomicAdd(&cnt, 1);
    for (int i = t; i < NBUCK; i += 256) gcur[i] = 0;
    stats[t] = 0.f;
    __syncthreads();
    if (t == 0) *flag = (cnt >= 192) ? 1 : 0;
}

// ---------------- GEMM1 (MFMA): h1 = x @ W1, + fused att1 dots --------------
// h1 is written SLICE-MAJOR: region k (k = col/16, 8 regions of 3.2 MB each)
// holds rows' k-th 16-col slice contiguously: h1[k*N*16 + row*16 + (col&15)].
__global__ __launch_bounds__(256) void k_gemm1(
    const void* __restrict__ x, const void* __restrict__ W1,
    const void* __restrict__ attS, const void* __restrict__ attD,
    const int* __restrict__ flag, unsigned short* __restrict__ h1,
    float* __restrict__ aS, float* __restrict__ aD)
{
    __shared__ __attribute__((aligned(16))) unsigned short wT[128*132]; // 33.8 KB
    const int isb = *flag;
    const int tid = threadIdx.x;
    if (isb) {
        const unsigned short* w = (const unsigned short*)W1;
        for (int idx = tid; idx < 128*128; idx += 256){
            int k = idx >> 7, n = idx & 127;
            wT[n*132 + k] = w[idx];
        }
    } else {
        const float* w = (const float*)W1;
        for (int idx = tid; idx < 128*128; idx += 256){
            int k = idx >> 7, n = idx & 127;
            wT[n*132 + k] = f2bb(w[idx]);
        }
    }
    __syncthreads();

    const int w4 = tid >> 6, lane = tid & 63, quad = lane >> 4, l16 = lane & 15;
    const int rowbase = blockIdx.x*32 + (w4 >> 1)*16;   // 3125*32 = 100000 exact
    const int colbase = (w4 & 1)*64;
    const int head = w4 & 1;

    s8v bfr[4][4];
    float asv[4], adv[4];
    #pragma unroll
    for (int ct = 0; ct < 4; ct++){
        int n = colbase + ct*16 + l16;
        asv[ct] = rdf(attS, n, isb);
        adv[ct] = rdf(attD, n, isb);
        #pragma unroll
        for (int s = 0; s < 4; s++){
            int k0 = s*32 + quad*8;
            const unsigned short* p = &wT[n*132 + k0];
            u2v a = *(const u2v*)p, b = *(const u2v*)(p+4);
            union { u4v u; s8v s; } cv; cv.u = (u4v){a[0],a[1],b[0],b[1]};
            bfr[ct][s] = cv.s;
        }
    }

    f4v acc[4];
    #pragma unroll
    for (int ct = 0; ct < 4; ct++) acc[ct] = (f4v){0.f,0.f,0.f,0.f};

    const int m = rowbase + l16;
    #pragma unroll
    for (int s = 0; s < 4; s++){
        int k0 = s*32 + quad*8;
        s8v af;
        if (isb){
            union { u4v u; s8v s; } cv;
            cv.u = *(const u4v*)((const unsigned short*)x + (size_t)m*128 + k0);
            af = cv.s;
        } else {
            const float* xp = (const float*)x + (size_t)m*128 + k0;
            f4v f0 = *(const f4v*)xp, f1 = *(const f4v*)(xp+4);
            union { u4v u; s8v s; } cv;
            cv.u = (u4v){pack2(f0[0],f0[1]), pack2(f0[2],f0[3]),
                         pack2(f1[0],f1[1]), pack2(f1[2],f1[3])};
            af = cv.s;
        }
        #pragma unroll
        for (int ct = 0; ct < 4; ct++)
            acc[ct] = __builtin_amdgcn_mfma_f32_16x16x32_bf16(af, bfr[ct][s], acc[ct], 0,0,0);
    }

    // C/D: col = lane&15, row = quad*4 + reg  -> slice-major store
    #pragma unroll
    for (int ct = 0; ct < 4; ct++){
        int col = colbase + ct*16 + l16;
        int slc = col >> 4;
        #pragma unroll
        for (int r = 0; r < 4; r++){
            int row = rowbase + quad*4 + r;
            h1[(size_t)slc*(N_NODES*16) + (size_t)row*16 + (col & 15)]
                = f2bb(acc[ct][r]);
        }
    }

    // fused att1: per row, reduce acc*att over wave's 64 cols (one head).
    #pragma unroll
    for (int r = 0; r < 4; r++){
        float vs = 0.f, vd = 0.f;
        #pragma unroll
        for (int ct = 0; ct < 4; ct++){ vs += acc[ct][r]*asv[ct]; vd += acc[ct][r]*adv[ct]; }
        #pragma unroll
        for (int o = 1; o < 16; o <<= 1){
            vs += __shfl_xor(vs, o, 64);
            vd += __shfl_xor(vd, o, 64);
        }
        if (l16 == 0){
            int row = rowbase + quad*4 + r;
            aS[row*2 + head] = vs;
            aD[row*2 + head] = vd;
        }
    }
}

// ---------------- CSR pass 1: LDS-binned coarse scatter ---------------------
__global__ __launch_bounds__(256) void k_bin(
    const int* __restrict__ esrc, const int* __restrict__ edst,
    int* __restrict__ gcur, uint32_t* __restrict__ staging)
{
    __shared__ int cnt[NBUCK];
    __shared__ int bb[NBUCK];
    const int t = threadIdx.x;
    for (int i = t; i < NBUCK; i += 256) cnt[i] = 0;
    __syncthreads();
    const int e0 = blockIdx.x * EPB;
    const int e1 = (e0 + EPB < ET) ? e0 + EPB : ET;
    for (int e = e0 + t; e < e1; e += 256){
        int d = (e < N_EDGES) ? edst[e] : e - N_EDGES;
        atomicAdd(&cnt[d >> 8], 1);
    }
    __syncthreads();
    // rotate flush order by block to avoid lockstep per-address atomic chains
    const int bofs = (int)(blockIdx.x % NBUCK);
    for (int i = t; i < NBUCK; i += 256){
        int bkt = i + bofs; if (bkt >= NBUCK) bkt -= NBUCK;
        int c = cnt[bkt];
        bb[bkt] = c ? atomicAdd(&gcur[bkt], c) : 0;
        cnt[bkt] = 0;
    }
    __syncthreads();
    for (int e = e0 + t; e < e1; e += 256){
        int d, s;
        if (e < N_EDGES){ s = esrc[e]; d = edst[e]; } else { s = d = e - N_EDGES; }
        int b = d >> 8;
        int r = atomicAdd(&cnt[b], 1);
        int p = bb[b] + r;
        if (p < BCAP) staging[(size_t)b*BCAP + p] = ((uint32_t)s << 8) | (uint32_t)(d & 255);
    }
}

// ---------------- CSR pass 2: per-bucket fine counting sort (R3 form) -------
// Writes sorted plain src ids back into the staging buffer (k_wts transforms
// them in place to weight records).
__global__ __launch_bounds__(256) void k_sort(
    const int* __restrict__ gcur, uint32_t* stg,
    int* __restrict__ deg, int* __restrict__ cur)
{
    __shared__ int h[256], sc[256], rk[256];
    __shared__ int lsrc[BCAP];
    const int b = blockIdx.x;
    const int t = threadIdx.x;
    const int base = b * BCAP;
    int cnt = gcur[b];
    if (cnt > BCAP) cnt = BCAP;
    h[t] = 0; rk[t] = 0;
    __syncthreads();
    for (int i = t; i < cnt; i += 256)
        atomicAdd(&h[stg[base + i] & 255u], 1);
    __syncthreads();
    sc[t] = h[t];
    __syncthreads();
    for (int off = 1; off < 256; off <<= 1){
        int v = (t >= off) ? sc[t - off] : 0;
        __syncthreads();
        sc[t] += v;
        __syncthreads();
    }
    int dg = b*256 + t;
    if (dg < N_NODES){
        deg[dg] = h[t];
        cur[dg] = base + sc[t];    // end pointer; start = end - deg
    }
    __syncthreads();
    for (int i = t; i < cnt; i += 256){
        uint32_t w = stg[base + i];
        int dl = w & 255u;
        int r = atomicAdd(&rk[dl], 1);
        lsrc[sc[dl] - h[dl] + r] = (int)(w >> 8);
    }
    __syncthreads();
    for (int i = t; i < cnt; i += 256) stg[base + i] = (uint32_t)lsrc[i];
}

// ---------------- layer-1 weights: 8 lanes/node, in-place transform ---------
// Reads plain src from wb0 (written by k_sort), computes both heads' exps
// ONCE, rewrites wb0[j] = (src<<15)|half_bits(e0) (half has no sign bit:
// encoding exact), wb1[j] = (src<<15)|half_bits(e1); per-node float dens.
__global__ __launch_bounds__(256) void k_wts(
    const int* __restrict__ cur, const int* __restrict__ deg,
    uint32_t* __restrict__ wb0, uint32_t* __restrict__ wb1,
    const float* __restrict__ aS, const float* __restrict__ aD,
    float* __restrict__ den)
{
    const int l = threadIdx.x & 63;
    const int wv = threadIdx.x >> 6;
    const int g = l >> 3, gl = l & 7;          // 8 groups of 8 lanes per wave
    const int d = blockIdx.x*32 + wv*8 + g;    // 3125*32 = 100000 exact
    int end   = cur[d];
    int start = end - deg[d];
    float2 ad = *(const float2*)(aD + (size_t)d*2);
    float dn0 = 0.f, dn1 = 0.f;
    for (int j = start + gl; j < end; j += 8){
        uint32_t s = wb0[j];
        float2 as = *(const float2*)(aS + (size_t)s*2);
        float al0 = as.x + ad.x, al1 = as.y + ad.y;
        al0 = al0 > 0.f ? al0 : NEG*al0;
        al1 = al1 > 0.f ? al1 : NEG*al1;
        float e0 = __expf(al0), e1 = __expf(al1);
        dn0 += e0; dn1 += e1;
        uint32_t sb = s << 15;
        wb0[j] = sb | ((uint32_t)__half_as_ushort(__float2half(e0)) & 0x7FFFu);
        wb1[j] = sb | ((uint32_t)__half_as_ushort(__float2half(e1)) & 0x7FFFu);
    }
    #pragma unroll
    for (int o = 1; o < 8; o <<= 1){
        dn0 += __shfl_xor(dn0, o, 64);
        dn1 += __shfl_xor(dn1, o, 64);
    }
    if (gl == 0){
        den[(size_t)d*2]     = dn0;
        den[(size_t)d*2 + 1] = dn1;
    }
}

// ---------------- layer-1 agg: slice-major 8-way XCD split, zero-fold -------
// Task = (node, slice), slice = blockIdx&7 -> XCD-resident 3.2 MB h1 region
// (proven R7: FETCH ~= compulsory). NEW structure kills R7's overhead: 8
// lanes per task, lane gl OWNS cols 2gl,2gl+1 (one dword of the 32B slice).
// Edges stream sequentially per group, 4-deep unroll (4 gathers in flight,
// 2 independent acc pairs). NO shuffle fold, no rm uniformization, epilogue
// = normalize + single dword store. wb loads are group-uniform (broadcast).
__global__ __launch_bounds__(256) void k_agg1(
    const int* __restrict__ cur, const int* __restrict__ deg,
    const uint32_t* __restrict__ wb0, const uint32_t* __restrict__ wb1,
    const float* __restrict__ den, const uint32_t* __restrict__ h1u,
    uint32_t* __restrict__ out1u)
{
    const int bx = blockIdx.x;
    const int k = bx & 7;                // slice class -> XCD affinity
    const int grp = bx >> 3;             // 3125 groups x 32 node-slices
    const int h = k >> 2;                // head: slices 0-3 h0, 4-7 h1
    const uint32_t* __restrict__ wb = h ? wb1 : wb0;
    const int l = threadIdx.x & 63;
    const int wv = threadIdx.x >> 6;
    const int g = l >> 3, gl = l & 7;
    const int d = grp*32 + wv*8 + g;     // < 100000 exact
    const char* hb = (const char*)h1u + (size_t)k*(N_NODES*32) + gl*4;
    int end   = cur[d];
    int start = end - deg[d];
    float dh = den[(size_t)d*2 + h];
    float a0 = 0.f, a1 = 0.f, b0 = 0.f, b1 = 0.f;
    int j = start;
    for (; j + 4 <= end; j += 4){
        uint32_t w0 = __builtin_nontemporal_load(wb + j);
        uint32_t w1 = __builtin_nontemporal_load(wb + j + 1);
        uint32_t w2 = __builtin_nontemporal_load(wb + j + 2);
        uint32_t w3 = __builtin_nontemporal_load(wb + j + 3);
        uint32_t G0 = *(const uint32_t*)(hb + ((size_t)(w0 >> 15) << 5));
        uint32_t G1 = *(const uint32_t*)(hb + ((size_t)(w1 >> 15) << 5));
        uint32_t G2 = *(const uint32_t*)(hb + ((size_t)(w2 >> 15) << 5));
        uint32_t G3 = *(const uint32_t*)(hb + ((size_t)(w3 >> 15) << 5));
        float f0 = w15f(w0), f1 = w15f(w1), f2 = w15f(w2), f3 = w15f(w3);
        a0 += f0*lo16(G0); a1 += f0*hi16(G0);
        b0 += f1*lo16(G1); b1 += f1*hi16(G1);
        a0 += f2*lo16(G2); a1 += f2*hi16(G2);
        b0 += f3*lo16(G3); b1 += f3*hi16(G3);
    }
    for (; j < end; j++){
        uint32_t w0 = __builtin_nontemporal_load(wb + j);
        uint32_t G0 = *(const uint32_t*)(hb + ((size_t)(w0 >> 15) << 5));
        float f0 = w15f(w0);
        a0 += f0*lo16(G0); a1 += f0*hi16(G0);
    }
    a0 += b0; a1 += b1;
    float rr = 1.f / fmaxf(dh, 1e-20f);
    out1u[(size_t)d*64 + k*8 + gl] = pack2(a0*rr, a1*rr);
}

// ---------------- BatchNorm stats: per-block LDS reduce, then 1 atomic ------
__global__ __launch_bounds__(256) void k_bnstats(
    const uint32_t* __restrict__ out1u, float* __restrict__ stats)
{
    __shared__ float red[4][64][4];      // wave x feat-pair x {s0,s1,q0,q1} = 4 KB
    int fp = threadIdx.x & 63;
    int wv = threadIdx.x >> 6;
    float s0 = 0.f, q0 = 0.f, s1 = 0.f, q1 = 0.f;
    for (int r = blockIdx.x*4 + wv; r < N_NODES; r += 512){
        uint32_t u = out1u[(size_t)r*64 + fp];
        float f0 = lo16(u), f1 = hi16(u);
        s0 += f0; q0 += f0*f0; s1 += f1; q1 += f1*f1;
    }
    red[wv][fp][0] = s0; red[wv][fp][1] = s1;
    red[wv][fp][2] = q0; red[wv][fp][3] = q1;
    __syncthreads();
    if (threadIdx.x < 64){
        int l = threadIdx.x;
        float a0=0.f, a1=0.f, b0=0.f, b1=0.f;
        #pragma unroll
        for (int w = 0; w < 4; w++){
            a0 += red[w][l][0]; a1 += red[w][l][1];
            b0 += red[w][l][2]; b1 += red[w][l][3];
        }
        unsafeAtomicAdd(&stats[2*l],       a0);
        unsafeAtomicAdd(&stats[2*l+1],     a1);
        unsafeAtomicAdd(&stats[128+2*l],   b0);
        unsafeAtomicAdd(&stats[128+2*l+1], b1);
    }
}

// ---------------- GEMM2 (MFMA): h2 = BN(out1) @ W2, + fused att2, BN-fin ----
__global__ __launch_bounds__(256) void k_gemm2(
    const unsigned short* __restrict__ out1b, const float* __restrict__ stats,
    const void* __restrict__ gamma, const void* __restrict__ beta,
    const void* __restrict__ W2, const void* __restrict__ attS,
    const void* __restrict__ attD, const int* __restrict__ flag,
    unsigned short* __restrict__ h2, float* __restrict__ aS, float* __restrict__ aD)
{
    __shared__ __attribute__((aligned(16))) unsigned short wT[80*132]; // 21.1 KB
    __shared__ float scl[128], shl[128];
    const int isb = *flag;
    const int tid = threadIdx.x;
    for (int idx = tid; idx < 128*80; idx += 256){
        int k = idx / 80, n = idx - k*80;
        wT[n*132 + k] = isb ? ((const unsigned short*)W2)[idx]
                            : f2bb(((const float*)W2)[idx]);
    }
    if (tid < 128){   // inline BN finalize
        float mean = stats[tid] * (1.f / N_NODES);
        float var = fmaxf(stats[128+tid] * (1.f / N_NODES) - mean*mean, 0.f);
        float rs = rsqrtf(var + BN_EPS);
        float sc = rdf(gamma, tid, isb) * rs;
        scl[tid] = sc;
        shl[tid] = rdf(beta, tid, isb) - mean*sc;
    }
    __syncthreads();

    const int w4 = tid >> 6, lane = tid & 63, quad = lane >> 4, l16 = lane & 15;
    const int rowbase = blockIdx.x*64 + w4*16;

    s8v bfr[5][4];
    float asv[5], adv[5];
    #pragma unroll
    for (int ct = 0; ct < 5; ct++){
        int n = ct*16 + l16;
        asv[ct] = rdf(attS, n, isb);
        adv[ct] = rdf(attD, n, isb);
        #pragma unroll
        for (int s = 0; s < 4; s++){
            int k0 = s*32 + quad*8;
            const unsigned short* p = &wT[n*132 + k0];
            u2v a = *(const u2v*)p, b = *(const u2v*)(p+4);
            union { u4v u; s8v s; } cv; cv.u = (u4v){a[0],a[1],b[0],b[1]};
            bfr[ct][s] = cv.s;
        }
    }

    f4v acc[5];
    #pragma unroll
    for (int ct = 0; ct < 5; ct++) acc[ct] = (f4v){0.f,0.f,0.f,0.f};

    int m = rowbase + l16;
    int mc = m < N_NODES ? m : N_NODES - 1;
    #pragma unroll
    for (int s = 0; s < 4; s++){
        int k0 = s*32 + quad*8;
        union { u4v u; s8v s8; } cin;
        cin.u = *(const u4v*)(out1b + (size_t)mc*128 + k0);
        u4v up;
        #pragma unroll
        for (int i = 0; i < 4; i++){
            float f0 = lo16(cin.u[i]), f1 = hi16(cin.u[i]);
            int k = k0 + 2*i;
            up[i] = pack2(f0*scl[k] + shl[k], f1*scl[k+1] + shl[k+1]);
        }
        union { u4v u; s8v s8; } cv; cv.u = up;
        #pragma unroll
        for (int ct = 0; ct < 5; ct++)
            acc[ct] = __builtin_amdgcn_mfma_f32_16x16x32_bf16(cv.s8, bfr[ct][s], acc[ct], 0,0,0);
    }

    #pragma unroll
    for (int ct = 0; ct < 5; ct++){
        int col = ct*16 + l16;
        #pragma unroll
        for (int r = 0; r < 4; r++){
            int row = rowbase + quad*4 + r;
            if (row < N_NODES) h2[(size_t)row*80 + col] = f2bb(acc[ct][r]);
        }
    }

    // fused att2: head0 = cols 0..39, head1 = cols 40..79.
    #pragma unroll
    for (int r = 0; r < 4; r++){
        float vs0 = 0.f, vs1 = 0.f, vd0 = 0.f, vd1 = 0.f;
        #pragma unroll
        for (int ct = 0; ct < 5; ct++){
            int col = ct*16 + l16;
            float ps = acc[ct][r]*asv[ct], pd = acc[ct][r]*adv[ct];
            if (col < 40){ vs0 += ps; vd0 += pd; } else { vs1 += ps; vd1 += pd; }
        }
        #pragma unroll
        for (int o = 1; o < 16; o <<= 1){
            vs0 += __shfl_xor(vs0, o, 64); vs1 += __shfl_xor(vs1, o, 64);
            vd0 += __shfl_xor(vd0, o, 64); vd1 += __shfl_xor(vd1, o, 64);
        }
        if (l16 == 0){
            int row = rowbase + quad*4 + r;
            if (row < N_NODES){
                aS[row*2 + 0] = vs0; aS[row*2 + 1] = vs1;
                aD[row*2 + 0] = vd0; aD[row*2 + 1] = vd1;
            }
        }
    }
}

// ---------------- layer-2 agg: 2 nodes/wave, 10 lanes/edge x dwordx4 --------
// (R3 form — best measured.) src decoded from wb0 records (w >> 15).
__global__ __launch_bounds__(256) void k_agg2(
    const int* __restrict__ cur, const int* __restrict__ deg,
    const uint32_t* __restrict__ wb0, const float* __restrict__ aS,
    const float* __restrict__ aD, const uint32_t* __restrict__ h2u,
    const void* __restrict__ b2v, const int* __restrict__ flag,
    void* __restrict__ out)
{
    __shared__ uint2 lse[4][2][CH2 + 4];   // 16.6 KB
    const int wv = threadIdx.x >> 6;
    const int l = threadIdx.x & 63;
    const int half = l >> 5, ll = l & 31;
    const int d = blockIdx.x*8 + wv*2 + half;   // 12500*8 = 100000 exact
    const int isb = *flag;
    const int c = ll % 10;               // feature slot within edge
    const int g = ll / 10;               // edge group 0..2 (3 = idle lanes)
    const bool act = ll < 30;
    const int gq = act ? g : 0;          // safe lse index for idle lanes
    const uint32_t c16 = (uint32_t)(c*16);
    int end   = cur[d];
    int start = end - deg[d];
    float2 ad = *(const float2*)(aD + d*2);
    const int sh = (c >= 5) ? 16 : 0;    // cols 8c..8c+7: head1 iff 8c >= 40
    float den0 = 0.f, den1 = 0.f;
    float acc[8];
    #pragma unroll
    for (int k = 0; k < 8; k++) acc[k] = 0.f;
    const char* hb = (const char*)h2u;

#define G2(P, W) { u4v Gx = *(const u4v*)(hb + ((P).x + c16)); \
    float Wf = (W); \
    acc[0] += Wf*lo16(Gx[0]); acc[1] += Wf*hi16(Gx[0]); \
    acc[2] += Wf*lo16(Gx[1]); acc[3] += Wf*hi16(Gx[1]); \
    acc[4] += Wf*lo16(Gx[2]); acc[5] += Wf*hi16(Gx[2]); \
    acc[6] += Wf*lo16(Gx[3]); acc[7] += Wf*hi16(Gx[3]); }

    for (int c0 = start; c0 < end; c0 += CH2){
        int c1 = (c0 + CH2 < end) ? c0 + CH2 : end;
        int n = c1 - c0;
        // phase 1: half's 32 lanes parallel over this node's edges
        for (int j = c0 + ll; j < c1; j += 32){
            uint32_t s = __builtin_nontemporal_load(wb0 + j) >> 15;
            float2 as = *(const float2*)((const char*)aS + (s*8u));
            float al0 = as.x + ad.x, al1 = as.y + ad.y;
            al0 = al0 > 0.f ? al0 : NEG*al0;
            al1 = al1 > 0.f ? al1 : NEG*al1;
            float e0 = __expf(al0), e1 = __expf(al1);
            lse[wv][half][j - c0] = make_uint2(s * 160u, packh2(e0, e1));
            den0 += e0; den1 += e1;
        }
        int nn = ((n + 2) / 3) * 3;
        if (ll < nn - n) lse[wv][half][n + ll] = make_uint2(0u, 0u);
        // same-wave LDS RAW: in-order per wave, no block barrier needed
        int i = 0;
        for (; i + 9 <= nn; i += 9){     // 3 rounds of 3 edges in flight
            uint2 pa = lse[wv][half][i + gq];
            uint2 pb = lse[wv][half][i + 3 + gq];
            uint2 pc = lse[wv][half][i + 6 + gq];
            G2(pa, act ? hcvt(pa.y, sh) : 0.f);
            G2(pb, act ? hcvt(pb.y, sh) : 0.f);
            G2(pc, act ? hcvt(pc.y, sh) : 0.f);
        }
        for (; i < nn; i += 3){
            uint2 pa = lse[wv][half][i + gq];
            G2(pa, act ? hcvt(pa.y, sh) : 0.f);
        }
    }
#undef G2
    // den reduce within each half (both nodes share the 5 rounds)
    #pragma unroll
    for (int o = 1; o < 32; o <<= 1){
        den0 += __shfl_xor(den0, o, 64);
        den1 += __shfl_xor(den1, o, 64);
    }
    // fold the 3 edge-groups of each half: lanes ll<10 get g0+g1+g2.
    #pragma unroll
    for (int k = 0; k < 8; k++)
        acc[k] += __shfl(acc[k], l + 10, 64) + __shfl(acc[k], l + 20, 64);
    // lanes ll 0..9 hold totals for cols 8*ll..8*ll+7 of node d
    float r = 1.f / fmaxf((c < 5) ? den0 : den1, 1e-20f);
    #pragma unroll
    for (int k = 0; k < 8; k++) acc[k] *= r;

    // head-mean: lane ll<5 (classes 8ll..8ll+7, head0) pairs with ll+5 (head1)
    int lb = (ll < 5) ? ll : 0;
    float v[8];
    float mx = -1e30f;
    #pragma unroll
    for (int k = 0; k < 8; k++){
        float t = __shfl(acc[k], l + 5, 64);
        v[k] = 0.5f*(acc[k] + t) + rdf(b2v, 8*lb + k, isb);
        mx = fmaxf(mx, v[k]);
    }
    if (ll >= 5) mx = -1e30f;
    // log_softmax over 40 classes in lanes ll 0..4 x 8 slots (per half)
    mx = fmaxf(mx, __shfl_xor(mx, 1, 64));
    mx = fmaxf(mx, __shfl_xor(mx, 2, 64));
    mx = fmaxf(mx, __shfl_xor(mx, 4, 64));
    float ex = 0.f;
    if (ll < 5){
        #pragma unroll
        for (int k = 0; k < 8; k++) ex += __expf(v[k] - mx);
    }
    ex += __shfl_xor(ex, 1, 64);
    ex += __shfl_xor(ex, 2, 64);
    ex += __shfl_xor(ex, 4, 64);
    float lsf = __logf(ex);
    if (ll < 5){
        if (isb){
            u4v o;
            #pragma unroll
            for (int q = 0; q < 4; q++)
                o[q] = pack2(v[2*q] - mx - lsf, v[2*q+1] - mx - lsf);
            *(u4v*)((uint32_t*)out + (size_t)d*20 + 4*ll) = o;
        } else {
            float4 o0, o1;
            o0.x = v[0]-mx-lsf; o0.y = v[1]-mx-lsf; o0.z = v[2]-mx-lsf; o0.w = v[3]-mx-lsf;
            o1.x = v[4]-mx-lsf; o1.y = v[5]-mx-lsf; o1.z = v[6]-mx-lsf; o1.w = v[7]-mx-lsf;
            ((float4*)out)[(size_t)d*10 + 2*ll]     = o0;
            ((float4*)out)[(size_t)d*10 + 2*ll + 1] = o1;
        }
    }
}

extern "C" void kernel_launch(void* const* d_in, const int* in_sizes, int n_in,
                              void* d_out, int out_size, void* d_ws, size_t ws_size,
                              hipStream_t stream)
{
    const void* x    = d_in[0];
    const int*  ei   = (const int*)d_in[1];
    const void* W1   = d_in[2];
    const void* as1  = d_in[3];
    const void* ad1  = d_in[4];
    // d_in[5] = b1: cancels exactly through BatchNorm mean subtraction
    const void* gamma = d_in[6];
    const void* beta  = d_in[7];
    const void* W2   = d_in[8];
    const void* as2  = d_in[9];
    const void* ad2  = d_in[10];
    const void* b2v  = d_in[11];
    const int* esrc = ei;
    const int* edst = ei + N_EDGES;

    // --- workspace: ~75 MB total (81.7 MB proven safe) ---
    char* ws = (char*)d_ws;
    size_t off = 0;
    auto alloc = [&](size_t bytes) {
        void* p = ws + off;
        off += (bytes + 255) & ~(size_t)255;
        return p;
    };
    int*   flag  = (int*)alloc(256);
    float* stats = (float*)alloc(sizeof(float)*256);
    int*   gcur  = (int*)alloc(sizeof(int)*NBUCK);
    float* aS1   = (float*)alloc(sizeof(float)*N_NODES*2);
    float* aD1   = (float*)alloc(sizeof(float)*N_NODES*2);
    float* aS2   = (float*)alloc(sizeof(float)*N_NODES*2);
    float* aD2   = (float*)alloc(sizeof(float)*N_NODES*2);
    float* den1  = (float*)alloc(sizeof(float)*N_NODES*2);                     // 0.8 MB
    int*   deg   = (int*)alloc(sizeof(int)*N_NODES);
    int*   cur   = (int*)alloc(sizeof(int)*N_NODES);
    uint32_t* staging = (uint32_t*)alloc(sizeof(uint32_t)*(size_t)NBUCK*BCAP); // 9.6 MB (becomes wb0)
    uint32_t* wb1 = (uint32_t*)alloc(sizeof(uint32_t)*(size_t)NBUCK*BCAP);     // 9.6 MB
    unsigned short* h1  = (unsigned short*)alloc(2*(size_t)N_NODES*HID);  // 25.6 MB
    unsigned short* out1 = (unsigned short*)alloc(2*(size_t)N_NODES*HID); // 25.6 MB
    unsigned short* h2  = h1;            // alias: h1 dead after k_agg1
    uint32_t* wb0 = staging;             // alias: staging holds srcs after k_sort,
                                         // then weight records after k_wts

    k_init<<<1, 256, 0, stream>>>((const uint32_t*)W1, flag, gcur, stats);
    k_gemm1<<<3125, 256, 0, stream>>>(x, W1, as1, ad1, flag, h1, aS1, aD1);
    k_bin<<<NBB, 256, 0, stream>>>(esrc, edst, gcur, staging);
    k_sort<<<NBUCK, 256, 0, stream>>>(gcur, staging, deg, cur);
    k_wts<<<3125, 256, 0, stream>>>(cur, deg, wb0, wb1, aS1, aD1, den1);
    k_agg1<<<25000, 256, 0, stream>>>(cur, deg, wb0, wb1, den1,
                                      (const uint32_t*)h1, (uint32_t*)out1);
    k_bnstats<<<128, 256, 0, stream>>>((const uint32_t*)out1, stats);
    k_gemm2<<<1563, 256, 0, stream>>>(out1, stats, gamma, beta, W2, as2, ad2,
                                      flag, h2, aS2, aD2);
    k_agg2<<<12500, 256, 0, stream>>>(cur, deg, wb0, aS2, aD2,
                                      (const uint32_t*)h2, b2v, flag, d_out);
}

// Round 9
// 505.935 us; speedup vs baseline: 1.0999x; 1.0400x over previous
//
#include <hip/hip_runtime.h>
#include <hip/hip_bf16.h>
#include <hip/hip_fp16.h>
#include <stdint.h>

#define N_NODES 100000
#define N_EDGES 1600000
#define ET (N_EDGES + N_NODES)   // edges + self-loops
#define HID 128
#define C2 40
#define F2 80
#define NEG 0.2f
#define BN_EPS 1e-5f
#define NBUCK 391                // ceil(100000/256) coarse buckets (256 nodes each)
#define BCAP 6144                // slots per bucket (mean 4608, sd 66 -> +23 sigma)
#define NBB 640                  // bin-pass blocks
#define EPB ((ET + NBB - 1) / NBB)
#define CH2 256                  // per-NODE LDS edge cache in k_agg2

typedef __hip_bfloat16 bf16;
typedef __attribute__((ext_vector_type(8))) short s8v;          // 8 bf16 MFMA A/B frag
typedef __attribute__((ext_vector_type(4))) float f4v;          // MFMA C/D frag
typedef __attribute__((ext_vector_type(4))) unsigned int u4v;
typedef __attribute__((ext_vector_type(2))) unsigned int u2v;

__device__ __forceinline__ float b2f(bf16 v){ return __bfloat162float(v); }
__device__ __forceinline__ float rdf(const void* p, size_t i, int isb){
    return isb ? b2f(((const bf16*)p)[i]) : ((const float*)p)[i];
}
__device__ __forceinline__ unsigned short f2bb(float v){
    bf16 h = __float2bfloat16(v);
    return *(unsigned short*)&h;
}
__device__ __forceinline__ uint32_t pack2(float a, float b){
    return (uint32_t)f2bb(a) | ((uint32_t)f2bb(b) << 16);
}
__device__ __forceinline__ uint32_t packh2(float a, float b){
    return (uint32_t)__half_as_ushort(__float2half(a))
         | ((uint32_t)__half_as_ushort(__float2half(b)) << 16);
}
__device__ __forceinline__ float lo16(uint32_t u){ return __uint_as_float(u << 16); }
__device__ __forceinline__ float hi16(uint32_t u){ return __uint_as_float(u & 0xFFFF0000u); }
__device__ __forceinline__ float hcvt(uint32_t w, int sh){
    return __half2float(__ushort_as_half((unsigned short)((w >> sh) & 0xFFFFu)));
}
// decode 15-bit (sign-stripped half) weight from a (src<<15)|w15 record
__device__ __forceinline__ float w15f(uint32_t w){
    return __half2float(__ushort_as_half((unsigned short)(w & 0x7FFFu)));
}

// ---------------- init: dtype flag + zero gcur/stats ------------------------
__global__ __launch_bounds__(256) void k_init(
    const uint32_t* __restrict__ w1bits, int* __restrict__ flag,
    int* __restrict__ gcur, float* __restrict__ stats)
{
    __shared__ int cnt;
    int t = threadIdx.x;
    if (t == 0) cnt = 0;
    __syncthreads();
    uint32_t b = w1bits[t];
    float lo = __uint_as_float((b & 0xFFFFu) << 16);
    float a = fabsf(lo);
    if (a > 1e-8f && a < 1.0f) atomicAdd(&cnt, 1);
    for (int i = t; i < NBUCK; i += 256) gcur[i] = 0;
    stats[t] = 0.f;
    __syncthreads();
    if (t == 0) *flag = (cnt >= 192) ? 1 : 0;
}

// ---------------- GEMM1 (MFMA): h1 = x @ W1, + fused att1 dots --------------
// h1 is written SLICE-MAJOR: region k (k = col/16, 8 regions of 3.2 MB each)
// holds rows' k-th 16-col slice contiguously: h1[k*N*16 + row*16 + (col&15)].
__global__ __launch_bounds__(256) void k_gemm1(
    const void* __restrict__ x, const void* __restrict__ W1,
    const void* __restrict__ attS, const void* __restrict__ attD,
    const int* __restrict__ flag, unsigned short* __restrict__ h1,
    float* __restrict__ aS, float* __restrict__ aD)
{
    __shared__ __attribute__((aligned(16))) unsigned short wT[128*132]; // 33.8 KB
    const int isb = *flag;
    const int tid = threadIdx.x;
    if (isb) {
        const unsigned short* w = (const unsigned short*)W1;
        for (int idx = tid; idx < 128*128; idx += 256){
            int k = idx >> 7, n = idx & 127;
            wT[n*132 + k] = w[idx];
        }
    } else {
        const float* w = (const float*)W1;
        for (int idx = tid; idx < 128*128; idx += 256){
            int k = idx >> 7, n = idx & 127;
            wT[n*132 + k] = f2bb(w[idx]);
        }
    }
    __syncthreads();

    const int w4 = tid >> 6, lane = tid & 63, quad = lane >> 4, l16 = lane & 15;
    const int rowbase = blockIdx.x*32 + (w4 >> 1)*16;   // 3125*32 = 100000 exact
    const int colbase = (w4 & 1)*64;
    const int head = w4 & 1;

    s8v bfr[4][4];
    float asv[4], adv[4];
    #pragma unroll
    for (int ct = 0; ct < 4; ct++){
        int n = colbase + ct*16 + l16;
        asv[ct] = rdf(attS, n, isb);
        adv[ct] = rdf(attD, n, isb);
        #pragma unroll
        for (int s = 0; s < 4; s++){
            int k0 = s*32 + quad*8;
            const unsigned short* p = &wT[n*132 + k0];
            u2v a = *(const u2v*)p, b = *(const u2v*)(p+4);
            union { u4v u; s8v s; } cv; cv.u = (u4v){a[0],a[1],b[0],b[1]};
            bfr[ct][s] = cv.s;
        }
    }

    f4v acc[4];
    #pragma unroll
    for (int ct = 0; ct < 4; ct++) acc[ct] = (f4v){0.f,0.f,0.f,0.f};

    const int m = rowbase + l16;
    #pragma unroll
    for (int s = 0; s < 4; s++){
        int k0 = s*32 + quad*8;
        s8v af;
        if (isb){
            union { u4v u; s8v s; } cv;
            cv.u = *(const u4v*)((const unsigned short*)x + (size_t)m*128 + k0);
            af = cv.s;
        } else {
            const float* xp = (const float*)x + (size_t)m*128 + k0;
            f4v f0 = *(const f4v*)xp, f1 = *(const f4v*)(xp+4);
            union { u4v u; s8v s; } cv;
            cv.u = (u4v){pack2(f0[0],f0[1]), pack2(f0[2],f0[3]),
                         pack2(f1[0],f1[1]), pack2(f1[2],f1[3])};
            af = cv.s;
        }
        #pragma unroll
        for (int ct = 0; ct < 4; ct++)
            acc[ct] = __builtin_amdgcn_mfma_f32_16x16x32_bf16(af, bfr[ct][s], acc[ct], 0,0,0);
    }

    // C/D: col = lane&15, row = quad*4 + reg  -> slice-major store
    #pragma unroll
    for (int ct = 0; ct < 4; ct++){
        int col = colbase + ct*16 + l16;
        int slc = col >> 4;
        #pragma unroll
        for (int r = 0; r < 4; r++){
            int row = rowbase + quad*4 + r;
            h1[(size_t)slc*(N_NODES*16) + (size_t)row*16 + (col & 15)]
                = f2bb(acc[ct][r]);
        }
    }

    // fused att1: per row, reduce acc*att over wave's 64 cols (one head).
    #pragma unroll
    for (int r = 0; r < 4; r++){
        float vs = 0.f, vd = 0.f;
        #pragma unroll
        for (int ct = 0; ct < 4; ct++){ vs += acc[ct][r]*asv[ct]; vd += acc[ct][r]*adv[ct]; }
        #pragma unroll
        for (int o = 1; o < 16; o <<= 1){
            vs += __shfl_xor(vs, o, 64);
            vd += __shfl_xor(vd, o, 64);
        }
        if (l16 == 0){
            int row = rowbase + quad*4 + r;
            aS[row*2 + head] = vs;
            aD[row*2 + head] = vd;
        }
    }
}

// ---------------- CSR pass 1: LDS-binned coarse scatter ---------------------
__global__ __launch_bounds__(256) void k_bin(
    const int* __restrict__ esrc, const int* __restrict__ edst,
    int* __restrict__ gcur, uint32_t* __restrict__ staging)
{
    __shared__ int cnt[NBUCK];
    __shared__ int bb[NBUCK];
    const int t = threadIdx.x;
    for (int i = t; i < NBUCK; i += 256) cnt[i] = 0;
    __syncthreads();
    const int e0 = blockIdx.x * EPB;
    const int e1 = (e0 + EPB < ET) ? e0 + EPB : ET;
    for (int e = e0 + t; e < e1; e += 256){
        int d = (e < N_EDGES) ? edst[e] : e - N_EDGES;
        atomicAdd(&cnt[d >> 8], 1);
    }
    __syncthreads();
    // rotate flush order by block to avoid lockstep per-address atomic chains
    const int bofs = (int)(blockIdx.x % NBUCK);
    for (int i = t; i < NBUCK; i += 256){
        int bkt = i + bofs; if (bkt >= NBUCK) bkt -= NBUCK;
        int c = cnt[bkt];
        bb[bkt] = c ? atomicAdd(&gcur[bkt], c) : 0;
        cnt[bkt] = 0;
    }
    __syncthreads();
    for (int e = e0 + t; e < e1; e += 256){
        int d, s;
        if (e < N_EDGES){ s = esrc[e]; d = edst[e]; } else { s = d = e - N_EDGES; }
        int b = d >> 8;
        int r = atomicAdd(&cnt[b], 1);
        int p = bb[b] + r;
        if (p < BCAP) staging[(size_t)b*BCAP + p] = ((uint32_t)s << 8) | (uint32_t)(d & 255);
    }
}

// ---------------- CSR pass 2: per-bucket fine counting sort (R3 form) -------
// Writes sorted plain src ids back into the staging buffer (k_wts transforms
// them in place to weight records).
__global__ __launch_bounds__(256) void k_sort(
    const int* __restrict__ gcur, uint32_t* stg,
    int* __restrict__ deg, int* __restrict__ cur)
{
    __shared__ int h[256], sc[256], rk[256];
    __shared__ int lsrc[BCAP];
    const int b = blockIdx.x;
    const int t = threadIdx.x;
    const int base = b * BCAP;
    int cnt = gcur[b];
    if (cnt > BCAP) cnt = BCAP;
    h[t] = 0; rk[t] = 0;
    __syncthreads();
    for (int i = t; i < cnt; i += 256)
        atomicAdd(&h[stg[base + i] & 255u], 1);
    __syncthreads();
    sc[t] = h[t];
    __syncthreads();
    for (int off = 1; off < 256; off <<= 1){
        int v = (t >= off) ? sc[t - off] : 0;
        __syncthreads();
        sc[t] += v;
        __syncthreads();
    }
    int dg = b*256 + t;
    if (dg < N_NODES){
        deg[dg] = h[t];
        cur[dg] = base + sc[t];    // end pointer; start = end - deg
    }
    __syncthreads();
    for (int i = t; i < cnt; i += 256){
        uint32_t w = stg[base + i];
        int dl = w & 255u;
        int r = atomicAdd(&rk[dl], 1);
        lsrc[sc[dl] - h[dl] + r] = (int)(w >> 8);
    }
    __syncthreads();
    for (int i = t; i < cnt; i += 256) stg[base + i] = (uint32_t)lsrc[i];
}

// ---------------- layer-1 weights: 8 lanes/node, in-place transform ---------
// Reads plain src from wb0 (written by k_sort), computes both heads' exps
// ONCE, rewrites wb0[j] = (src<<15)|half_bits(e0) (half has no sign bit:
// encoding exact), wb1[j] = (src<<15)|half_bits(e1); per-node float dens.
__global__ __launch_bounds__(256) void k_wts(
    const int* __restrict__ cur, const int* __restrict__ deg,
    uint32_t* __restrict__ wb0, uint32_t* __restrict__ wb1,
    const float* __restrict__ aS, const float* __restrict__ aD,
    float* __restrict__ den)
{
    const int l = threadIdx.x & 63;
    const int wv = threadIdx.x >> 6;
    const int g = l >> 3, gl = l & 7;          // 8 groups of 8 lanes per wave
    const int d = blockIdx.x*32 + wv*8 + g;    // 3125*32 = 100000 exact
    int end   = cur[d];
    int start = end - deg[d];
    float2 ad = *(const float2*)(aD + (size_t)d*2);
    float dn0 = 0.f, dn1 = 0.f;
    for (int j = start + gl; j < end; j += 8){
        uint32_t s = wb0[j];
        float2 as = *(const float2*)(aS + (size_t)s*2);
        float al0 = as.x + ad.x, al1 = as.y + ad.y;
        al0 = al0 > 0.f ? al0 : NEG*al0;
        al1 = al1 > 0.f ? al1 : NEG*al1;
        float e0 = __expf(al0), e1 = __expf(al1);
        dn0 += e0; dn1 += e1;
        uint32_t sb = s << 15;
        wb0[j] = sb | ((uint32_t)__half_as_ushort(__float2half(e0)) & 0x7FFFu);
        wb1[j] = sb | ((uint32_t)__half_as_ushort(__float2half(e1)) & 0x7FFFu);
    }
    #pragma unroll
    for (int o = 1; o < 8; o <<= 1){
        dn0 += __shfl_xor(dn0, o, 64);
        dn1 += __shfl_xor(dn1, o, 64);
    }
    if (gl == 0){
        den[(size_t)d*2]     = dn0;
        den[(size_t)d*2 + 1] = dn1;
    }
}

// ---------------- layer-1 agg: slice-major XCD split, coalesced wb ----------
// Task = (node, slice), slice = blockIdx&7 -> XCD-resident 3.2 MB h1 region
// (R7-proven: FETCH ~= compulsory). 8 lanes/task, lane gl owns cols 2gl,2gl+1
// (one dword). wb is read in per-group COALESCED 32B chunks (lane gl loads
// record base+gl, nt; full sector used) double-buffered 1 chunk ahead; each
// record is broadcast to the group's 8 lanes via shfl, so the 8 L2-hit
// gathers per chunk hide the next chunk's HBM latency. OOB edges get f=0
// (gather address clamped to a valid record - no divergence). out1 written
// with per-lane nt stores (no read-for-ownership RMW - R8's FETCH lesson).
__global__ __launch_bounds__(256) void k_agg1(
    const int* __restrict__ cur, const int* __restrict__ deg,
    const uint32_t* __restrict__ wb0, const uint32_t* __restrict__ wb1,
    const float* __restrict__ den, const uint32_t* __restrict__ h1u,
    uint32_t* __restrict__ out1u)
{
    const int bx = blockIdx.x;
    const int k = bx & 7;                // slice class -> XCD affinity
    const int grp = bx >> 3;             // 3125 groups x 32 node-slices
    const int h = k >> 2;                // head: slices 0-3 h0, 4-7 h1
    const uint32_t* __restrict__ wb = h ? wb1 : wb0;
    const int l = threadIdx.x & 63;
    const int wv = threadIdx.x >> 6;
    const int g = l >> 3, gl = l & 7;
    const int gbase = l & ~7;            // wave-lane index of group's lane 0
    const int d = grp*32 + wv*8 + g;     // < 100000 exact
    const char* hb = (const char*)h1u + (size_t)k*(N_NODES*32) + gl*4;
    int end   = cur[d];
    int start = end - deg[d];
    float dh = den[(size_t)d*2 + h];
    float a0 = 0.f, a1 = 0.f;

    int jA = start + gl;
    uint32_t recA = __builtin_nontemporal_load(wb + (jA < end ? jA : start));
    int base = start;
    while (base < end){
        uint32_t recCur = recA;
        int nb = base + 8;
        if (nb < end){
            int jN = nb + gl;
            recA = __builtin_nontemporal_load(wb + (jN < end ? jN : start));
        }
        int lim = end - base;            // group-uniform; >=1
        #pragma unroll
        for (int e = 0; e < 8; e++){
            uint32_t w = __shfl(recCur, gbase + e, 64);
            float f = (e < lim) ? w15f(w) : 0.f;
            uint32_t G = *(const uint32_t*)(hb + ((size_t)(w >> 15) << 5));
            a0 += f*lo16(G); a1 += f*hi16(G);
        }
        base = nb;
    }
    float rr = 1.f / fmaxf(dh, 1e-20f);
    uint32_t r = pack2(a0*rr, a1*rr);
    __builtin_nontemporal_store(r, out1u + (size_t)d*64 + k*8 + gl);
}

// ---------------- BatchNorm stats: per-block LDS reduce, then 1 atomic ------
__global__ __launch_bounds__(256) void k_bnstats(
    const uint32_t* __restrict__ out1u, float* __restrict__ stats)
{
    __shared__ float red[4][64][4];      // wave x feat-pair x {s0,s1,q0,q1} = 4 KB
    int fp = threadIdx.x & 63;
    int wv = threadIdx.x >> 6;
    float s0 = 0.f, q0 = 0.f, s1 = 0.f, q1 = 0.f;
    for (int r = blockIdx.x*4 + wv; r < N_NODES; r += 512){
        uint32_t u = out1u[(size_t)r*64 + fp];
        float f0 = lo16(u), f1 = hi16(u);
        s0 += f0; q0 += f0*f0; s1 += f1; q1 += f1*f1;
    }
    red[wv][fp][0] = s0; red[wv][fp][1] = s1;
    red[wv][fp][2] = q0; red[wv][fp][3] = q1;
    __syncthreads();
    if (threadIdx.x < 64){
        int l = threadIdx.x;
        float a0=0.f, a1=0.f, b0=0.f, b1=0.f;
        #pragma unroll
        for (int w = 0; w < 4; w++){
            a0 += red[w][l][0]; a1 += red[w][l][1];
            b0 += red[w][l][2]; b1 += red[w][l][3];
        }
        unsafeAtomicAdd(&stats[2*l],       a0);
        unsafeAtomicAdd(&stats[2*l+1],     a1);
        unsafeAtomicAdd(&stats[128+2*l],   b0);
        unsafeAtomicAdd(&stats[128+2*l+1], b1);
    }
}

// ---------------- GEMM2 (MFMA): h2 = BN(out1) @ W2, + fused att2, BN-fin ----
__global__ __launch_bounds__(256) void k_gemm2(
    const unsigned short* __restrict__ out1b, const float* __restrict__ stats,
    const void* __restrict__ gamma, const void* __restrict__ beta,
    const void* __restrict__ W2, const void* __restrict__ attS,
    const void* __restrict__ attD, const int* __restrict__ flag,
    unsigned short* __restrict__ h2, float* __restrict__ aS, float* __restrict__ aD)
{
    __shared__ __attribute__((aligned(16))) unsigned short wT[80*132]; // 21.1 KB
    __shared__ float scl[128], shl[128];
    const int isb = *flag;
    const int tid = threadIdx.x;
    for (int idx = tid; idx < 128*80; idx += 256){
        int k = idx / 80, n = idx - k*80;
        wT[n*132 + k] = isb ? ((const unsigned short*)W2)[idx]
                            : f2bb(((const float*)W2)[idx]);
    }
    if (tid < 128){   // inline BN finalize
        float mean = stats[tid] * (1.f / N_NODES);
        float var = fmaxf(stats[128+tid] * (1.f / N_NODES) - mean*mean, 0.f);
        float rs = rsqrtf(var + BN_EPS);
        float sc = rdf(gamma, tid, isb) * rs;
        scl[tid] = sc;
        shl[tid] = rdf(beta, tid, isb) - mean*sc;
    }
    __syncthreads();

    const int w4 = tid >> 6, lane = tid & 63, quad = lane >> 4, l16 = lane & 15;
    const int rowbase = blockIdx.x*64 + w4*16;

    s8v bfr[5][4];
    float asv[5], adv[5];
    #pragma unroll
    for (int ct = 0; ct < 5; ct++){
        int n = ct*16 + l16;
        asv[ct] = rdf(attS, n, isb);
        adv[ct] = rdf(attD, n, isb);
        #pragma unroll
        for (int s = 0; s < 4; s++){
            int k0 = s*32 + quad*8;
            const unsigned short* p = &wT[n*132 + k0];
            u2v a = *(const u2v*)p, b = *(const u2v*)(p+4);
            union { u4v u; s8v s; } cv; cv.u = (u4v){a[0],a[1],b[0],b[1]};
            bfr[ct][s] = cv.s;
        }
    }

    f4v acc[5];
    #pragma unroll
    for (int ct = 0; ct < 5; ct++) acc[ct] = (f4v){0.f,0.f,0.f,0.f};

    int m = rowbase + l16;
    int mc = m < N_NODES ? m : N_NODES - 1;
    #pragma unroll
    for (int s = 0; s < 4; s++){
        int k0 = s*32 + quad*8;
        union { u4v u; s8v s8; } cin;
        cin.u = *(const u4v*)(out1b + (size_t)mc*128 + k0);
        u4v up;
        #pragma unroll
        for (int i = 0; i < 4; i++){
            float f0 = lo16(cin.u[i]), f1 = hi16(cin.u[i]);
            int k = k0 + 2*i;
            up[i] = pack2(f0*scl[k] + shl[k], f1*scl[k+1] + shl[k+1]);
        }
        union { u4v u; s8v s8; } cv; cv.u = up;
        #pragma unroll
        for (int ct = 0; ct < 5; ct++)
            acc[ct] = __builtin_amdgcn_mfma_f32_16x16x32_bf16(cv.s8, bfr[ct][s], acc[ct], 0,0,0);
    }

    #pragma unroll
    for (int ct = 0; ct < 5; ct++){
        int col = ct*16 + l16;
        #pragma unroll
        for (int r = 0; r < 4; r++){
            int row = rowbase + quad*4 + r;
            if (row < N_NODES) h2[(size_t)row*80 + col] = f2bb(acc[ct][r]);
        }
    }

    // fused att2: head0 = cols 0..39, head1 = cols 40..79.
    #pragma unroll
    for (int r = 0; r < 4; r++){
        float vs0 = 0.f, vs1 = 0.f, vd0 = 0.f, vd1 = 0.f;
        #pragma unroll
        for (int ct = 0; ct < 5; ct++){
            int col = ct*16 + l16;
            float ps = acc[ct][r]*asv[ct], pd = acc[ct][r]*adv[ct];
            if (col < 40){ vs0 += ps; vd0 += pd; } else { vs1 += ps; vd1 += pd; }
        }
        #pragma unroll
        for (int o = 1; o < 16; o <<= 1){
            vs0 += __shfl_xor(vs0, o, 64); vs1 += __shfl_xor(vs1, o, 64);
            vd0 += __shfl_xor(vd0, o, 64); vd1 += __shfl_xor(vd1, o, 64);
        }
        if (l16 == 0){
            int row = rowbase + quad*4 + r;
            if (row < N_NODES){
                aS[row*2 + 0] = vs0; aS[row*2 + 1] = vs1;
                aD[row*2 + 0] = vd0; aD[row*2 + 1] = vd1;
            }
        }
    }
}

// ---------------- layer-2 agg: 2 nodes/wave, 10 lanes/edge x dwordx4 --------
// (R3 form — best measured.) src decoded from wb0 records (w >> 15).
__global__ __launch_bounds__(256) void k_agg2(
    const int* __restrict__ cur, const int* __restrict__ deg,
    const uint32_t* __restrict__ wb0, const float* __restrict__ aS,
    const float* __restrict__ aD, const uint32_t* __restrict__ h2u,
    const void* __restrict__ b2v, const int* __restrict__ flag,
    void* __restrict__ out)
{
    __shared__ uint2 lse[4][2][CH2 + 4];   // 16.6 KB
    const int wv = threadIdx.x >> 6;
    const int l = threadIdx.x & 63;
    const int half = l >> 5, ll = l & 31;
    const int d = blockIdx.x*8 + wv*2 + half;   // 12500*8 = 100000 exact
    const int isb = *flag;
    const int c = ll % 10;               // feature slot within edge
    const int g = ll / 10;               // edge group 0..2 (3 = idle lanes)
    const bool act = ll < 30;
    const int gq = act ? g : 0;          // safe lse index for idle lanes
    const uint32_t c16 = (uint32_t)(c*16);
    int end   = cur[d];
    int start = end - deg[d];
    float2 ad = *(const float2*)(aD + d*2);
    const int sh = (c >= 5) ? 16 : 0;    // cols 8c..8c+7: head1 iff 8c >= 40
    float den0 = 0.f, den1 = 0.f;
    float acc[8];
    #pragma unroll
    for (int k = 0; k < 8; k++) acc[k] = 0.f;
    const char* hb = (const char*)h2u;

#define G2(P, W) { u4v Gx = *(const u4v*)(hb + ((P).x + c16)); \
    float Wf = (W); \
    acc[0] += Wf*lo16(Gx[0]); acc[1] += Wf*hi16(Gx[0]); \
    acc[2] += Wf*lo16(Gx[1]); acc[3] += Wf*hi16(Gx[1]); \
    acc[4] += Wf*lo16(Gx[2]); acc[5] += Wf*hi16(Gx[2]); \
    acc[6] += Wf*lo16(Gx[3]); acc[7] += Wf*hi16(Gx[3]); }

    for (int c0 = start; c0 < end; c0 += CH2){
        int c1 = (c0 + CH2 < end) ? c0 + CH2 : end;
        int n = c1 - c0;
        // phase 1: half's 32 lanes parallel over this node's edges
        for (int j = c0 + ll; j < c1; j += 32){
            uint32_t s = __builtin_nontemporal_load(wb0 + j) >> 15;
            float2 as = *(const float2*)((const char*)aS + (s*8u));
            float al0 = as.x + ad.x, al1 = as.y + ad.y;
            al0 = al0 > 0.f ? al0 : NEG*al0;
            al1 = al1 > 0.f ? al1 : NEG*al1;
            float e0 = __expf(al0), e1 = __expf(al1);
            lse[wv][half][j - c0] = make_uint2(s * 160u, packh2(e0, e1));
            den0 += e0; den1 += e1;
        }
        int nn = ((n + 2) / 3) * 3;
        if (ll < nn - n) lse[wv][half][n + ll] = make_uint2(0u, 0u);
        // same-wave LDS RAW: in-order per wave, no block barrier needed
        int i = 0;
        for (; i + 9 <= nn; i += 9){     // 3 rounds of 3 edges in flight
            uint2 pa = lse[wv][half][i + gq];
            uint2 pb = lse[wv][half][i + 3 + gq];
            uint2 pc = lse[wv][half][i + 6 + gq];
            G2(pa, act ? hcvt(pa.y, sh) : 0.f);
            G2(pb, act ? hcvt(pb.y, sh) : 0.f);
            G2(pc, act ? hcvt(pc.y, sh) : 0.f);
        }
        for (; i < nn; i += 3){
            uint2 pa = lse[wv][half][i + gq];
            G2(pa, act ? hcvt(pa.y, sh) : 0.f);
        }
    }
#undef G2
    // den reduce within each half (both nodes share the 5 rounds)
    #pragma unroll
    for (int o = 1; o < 32; o <<= 1){
        den0 += __shfl_xor(den0, o, 64);
        den1 += __shfl_xor(den1, o, 64);
    }
    // fold the 3 edge-groups of each half: lanes ll<10 get g0+g1+g2.
    #pragma unroll
    for (int k = 0; k < 8; k++)
        acc[k] += __shfl(acc[k], l + 10, 64) + __shfl(acc[k], l + 20, 64);
    // lanes ll 0..9 hold totals for cols 8*ll..8*ll+7 of node d
    float r = 1.f / fmaxf((c < 5) ? den0 : den1, 1e-20f);
    #pragma unroll
    for (int k = 0; k < 8; k++) acc[k] *= r;

    // head-mean: lane ll<5 (classes 8ll..8ll+7, head0) pairs with ll+5 (head1)
    int lb = (ll < 5) ? ll : 0;
    float v[8];
    float mx = -1e30f;
    #pragma unroll
    for (int k = 0; k < 8; k++){
        float t = __shfl(acc[k], l + 5, 64);
        v[k] = 0.5f*(acc[k] + t) + rdf(b2v, 8*lb + k, isb);
        mx = fmaxf(mx, v[k]);
    }
    if (ll >= 5) mx = -1e30f;
    // log_softmax over 40 classes in lanes ll 0..4 x 8 slots (per half)
    mx = fmaxf(mx, __shfl_xor(mx, 1, 64));
    mx = fmaxf(mx, __shfl_xor(mx, 2, 64));
    mx = fmaxf(mx, __shfl_xor(mx, 4, 64));
    float ex = 0.f;
    if (ll < 5){
        #pragma unroll
        for (int k = 0; k < 8; k++) ex += __expf(v[k] - mx);
    }
    ex += __shfl_xor(ex, 1, 64);
    ex += __shfl_xor(ex, 2, 64);
    ex += __shfl_xor(ex, 4, 64);
    float lsf = __logf(ex);
    if (ll < 5){
        if (isb){
            u4v o;
            #pragma unroll
            for (int q = 0; q < 4; q++)
                o[q] = pack2(v[2*q] - mx - lsf, v[2*q+1] - mx - lsf);
            *(u4v*)((uint32_t*)out + (size_t)d*20 + 4*ll) = o;
        } else {
            float4 o0, o1;
            o0.x = v[0]-mx-lsf; o0.y = v[1]-mx-lsf; o0.z = v[2]-mx-lsf; o0.w = v[3]-mx-lsf;
            o1.x = v[4]-mx-lsf; o1.y = v[5]-mx-lsf; o1.z = v[6]-mx-lsf; o1.w = v[7]-mx-lsf;
            ((float4*)out)[(size_t)d*10 + 2*ll]     = o0;
            ((float4*)out)[(size_t)d*10 + 2*ll + 1] = o1;
        }
    }
}

extern "C" void kernel_launch(void* const* d_in, const int* in_sizes, int n_in,
                              void* d_out, int out_size, void* d_ws, size_t ws_size,
                              hipStream_t stream)
{
    const void* x    = d_in[0];
    const int*  ei   = (const int*)d_in[1];
    const void* W1   = d_in[2];
    const void* as1  = d_in[3];
    const void* ad1  = d_in[4];
    // d_in[5] = b1: cancels exactly through BatchNorm mean subtraction
    const void* gamma = d_in[6];
    const void* beta  = d_in[7];
    const void* W2   = d_in[8];
    const void* as2  = d_in[9];
    const void* ad2  = d_in[10];
    const void* b2v  = d_in[11];
    const int* esrc = ei;
    const int* edst = ei + N_EDGES;

    // --- workspace: ~75 MB total (81.7 MB proven safe) ---
    char* ws = (char*)d_ws;
    size_t off = 0;
    auto alloc = [&](size_t bytes) {
        void* p = ws + off;
        off += (bytes + 255) & ~(size_t)255;
        return p;
    };
    int*   flag  = (int*)alloc(256);
    float* stats = (float*)alloc(sizeof(float)*256);
    int*   gcur  = (int*)alloc(sizeof(int)*NBUCK);
    float* aS1   = (float*)alloc(sizeof(float)*N_NODES*2);
    float* aD1   = (float*)alloc(sizeof(float)*N_NODES*2);
    float* aS2   = (float*)alloc(sizeof(float)*N_NODES*2);
    float* aD2   = (float*)alloc(sizeof(float)*N_NODES*2);
    float* den1  = (float*)alloc(sizeof(float)*N_NODES*2);                     // 0.8 MB
    int*   deg   = (int*)alloc(sizeof(int)*N_NODES);
    int*   cur   = (int*)alloc(sizeof(int)*N_NODES);
    uint32_t* staging = (uint32_t*)alloc(sizeof(uint32_t)*(size_t)NBUCK*BCAP); // 9.6 MB (becomes wb0)
    uint32_t* wb1 = (uint32_t*)alloc(sizeof(uint32_t)*(size_t)NBUCK*BCAP);     // 9.6 MB
    unsigned short* h1  = (unsigned short*)alloc(2*(size_t)N_NODES*HID);  // 25.6 MB
    unsigned short* out1 = (unsigned short*)alloc(2*(size_t)N_NODES*HID); // 25.6 MB
    unsigned short* h2  = h1;            // alias: h1 dead after k_agg1
    uint32_t* wb0 = staging;             // alias: staging holds srcs after k_sort,
                                         // then weight records after k_wts

    k_init<<<1, 256, 0, stream>>>((const uint32_t*)W1, flag, gcur, stats);
    k_gemm1<<<3125, 256, 0, stream>>>(x, W1, as1, ad1, flag, h1, aS1, aD1);
    k_bin<<<NBB, 256, 0, stream>>>(esrc, edst, gcur, staging);
    k_sort<<<NBUCK, 256, 0, stream>>>(gcur, staging, deg, cur);
    k_wts<<<3125, 256, 0, stream>>>(cur, deg, wb0, wb1, aS1, aD1, den1);
    k_agg1<<<25000, 256, 0, stream>>>(cur, deg, wb0, wb1, den1,
                                      (const uint32_t*)h1, (uint32_t*)out1);
    k_bnstats<<<128, 256, 0, stream>>>((const uint32_t*)out1, stats);
    k_gemm2<<<1563, 256, 0, stream>>>(out1, stats, gamma, beta, W2, as2, ad2,
                                      flag, h2, aS2, aD2);
    k_agg2<<<12500, 256, 0, stream>>>(cur, deg, wb0, aS2, aD2,
                                      (const uint32_t*)h2, b2v, flag, d_out);
}